// Round 1
// baseline (260.922 us; speedup 1.0000x reference)
//
#include <hip/hip_runtime.h>

#define N_ 2048
#define S_ 16
#define D_ 128
#define H_ 8
#define EPS_ 1e-5f

typedef unsigned short ushortT;
typedef unsigned int uint32;
typedef __attribute__((ext_vector_type(8))) short short8;
typedef __attribute__((ext_vector_type(8))) unsigned short ushort8;
typedef __attribute__((ext_vector_type(4))) float f32x4;
typedef __attribute__((ext_vector_type(4))) unsigned int uint4v;
typedef __attribute__((ext_vector_type(8))) float float8;

__device__ __forceinline__ ushortT f2bf(float f) {
  union { float f; uint32 u; } c; c.f = f;
  uint32 u = c.u;
  u = (u + 0x7FFFu + ((u >> 16) & 1u)) >> 16;  // RNE
  return (ushortT)u;
}
__device__ __forceinline__ float bf2f(ushortT b) {
  union { uint32 u; float f; } c; c.u = ((uint32)b) << 16;
  return c.f;
}

// ---------------------------------------------------------------------------
// K0: per-(n,d) column: stable-descending ranks over S=16, diff + enc (bf16)
// All loops fully unrolled with constant bounds -> no dynamic register indexing.
// ---------------------------------------------------------------------------
__global__ __launch_bounds__(256) void k_prep(const float* __restrict__ x,
                                              ushortT* __restrict__ enc,
                                              ushortT* __restrict__ diff) {
  int g = blockIdx.x * 256 + threadIdx.x;  // N*D = 262144 threads
  int n = g >> 7, d = g & 127;
  const float* xp = x + (size_t)n * (S_ * D_) + d;
  float v[S_];
#pragma unroll
  for (int s = 0; s < S_; ++s) v[s] = xp[s * D_];
  int r[S_];
#pragma unroll
  for (int i = 0; i < S_; ++i) {
    int ri = 0;
#pragma unroll
    for (int j = 0; j < S_; ++j)
      ri += ((v[j] > v[i]) || (v[j] == v[i] && j < i)) ? 1 : 0;
    r[i] = ri;  // descending rank, stable on ties (matches jnp.argsort(-x))
  }
  float xs[S_ + 1];
#pragma unroll
  for (int s = 0; s < S_; ++s) {
    float acc = 0.f;
#pragma unroll
    for (int i = 0; i < S_; ++i) acc += (r[i] == s) ? v[i] : 0.f;
    xs[s] = acc;
  }
  xs[S_] = 0.f;
  ushortT* ep = enc + (size_t)n * (S_ * D_) + d;
  ushortT* dp = diff + (size_t)n * (S_ * D_) + d;
#pragma unroll
  for (int s = 0; s < S_; ++s) {
    uint32 mm = 0;
#pragma unroll
    for (int i = 0; i < S_; ++i) mm |= (r[i] <= s) ? (1u << i) : 0u;
    ep[s * D_] = f2bf((float)mm * (1.f / 65536.f));
    dp[s * D_] = f2bf(xs[s] - xs[s + 1]);
  }
}

// ---------------------------------------------------------------------------
// K0b: Wi[h][s][d][o] f32 -> Wit[h][s][o][d] bf16 (transposed per (h,s) tile)
// ---------------------------------------------------------------------------
__global__ __launch_bounds__(256) void k_castWi(const float* __restrict__ Wi,
                                                ushortT* __restrict__ Wit) {
  __shared__ ushortT tile[D_ * 136];
  int hs = blockIdx.x;  // h*16+s
  const float* src = Wi + (size_t)hs * D_ * D_;
  int t = threadIdx.x;
#pragma unroll 4
  for (int i = 0; i < 64; ++i) {  // 16384 / 256
    int e = t + 256 * i;
    int dd = e >> 7, o = e & 127;
    tile[dd * 136 + o] = f2bf(src[e]);
  }
  __syncthreads();
  int o = t >> 1, dbase = (t & 1) * 64;
  ushortT* dst = Wit + ((size_t)hs * D_ + o) * D_ + dbase;
#pragma unroll
  for (int c = 0; c < 8; ++c) {
    uint4v pk;
#pragma unroll
    for (int q = 0; q < 4; ++q) {
      ushortT lo = tile[(dbase + c * 8 + q * 2) * 136 + o];
      ushortT hi = tile[(dbase + c * 8 + q * 2 + 1) * 136 + o];
      pk[q] = (uint32)lo | ((uint32)hi << 16);
    }
    *(uint4v*)(dst + c * 8) = pk;
  }
}

// ---------------------------------------------------------------------------
// K0c: Wj[h][s][dd][o] f32 -> Wjt[h][o][s*256+dd] bf16, in two dd-halves
// ---------------------------------------------------------------------------
__global__ __launch_bounds__(256) void k_castWj(const float* __restrict__ Wj,
                                                ushortT* __restrict__ Wjt) {
  __shared__ ushortT tile[128 * 136];
  int hs = blockIdx.x; int h = hs >> 4, s = hs & 15;
  const float* src = Wj + (size_t)hs * 256 * D_;
  int t = threadIdx.x;
  for (int half = 0; half < 2; ++half) {
#pragma unroll 4
    for (int i = 0; i < 64; ++i) {
      int e = t + 256 * i;
      int dd = e >> 7, o = e & 127;
      tile[dd * 136 + o] = f2bf(src[half * 16384 + e]);
    }
    __syncthreads();
    int o = t >> 1, db = (t & 1) * 64;
    ushortT* dst = Wjt + ((size_t)(h * D_ + o)) * (S_ * 256) + s * 256 + half * 128 + db;
#pragma unroll
    for (int c = 0; c < 8; ++c) {
      uint4v pk;
#pragma unroll
      for (int q = 0; q < 4; ++q) {
        ushortT lo = tile[(db + c * 8 + q * 2) * 136 + o];
        ushortT hi = tile[(db + c * 8 + q * 2 + 1) * 136 + o];
        pk[q] = (uint32)lo | ((uint32)hi << 16);
      }
      *(uint4v*)(dst + c * 8) = pk;
    }
    __syncthreads();
  }
}

// ---------------------------------------------------------------------------
// K1: se[b,h,s,:] = enc[b,s,:] @ Wi[h,s] ; also per-(s,b,h) sum/sumsq partials
// M-tile 128(b) x N=128(o), K=128. XOR-swizzled LDS (G4).
// ---------------------------------------------------------------------------
__global__ __launch_bounds__(256) void k_gemm1(const ushortT* __restrict__ enc,
                                               const ushortT* __restrict__ Wit,
                                               ushortT* __restrict__ se,
                                               float* __restrict__ ssum,
                                               float* __restrict__ ssq) {
  int bt = blockIdx.x, s = blockIdx.y, h = blockIdx.z;
  __shared__ ushortT As[128 * 128];
  __shared__ ushortT Bs[128 * 128];
  int tid = threadIdx.x;
#pragma unroll
  for (int i = 0; i < 8; ++i) {
    int c = tid + 256 * i;
    int row = c >> 4, c16 = c & 15;
    int sw = ((c16 ^ (row & 7)) * 8);
    uint4v va = *(const uint4v*)(enc + (size_t)(bt * 128 + row) * (S_ * D_) + s * D_ + c16 * 8);
    *(uint4v*)(As + row * 128 + sw) = va;
    uint4v vb = *(const uint4v*)(Wit + ((size_t)((h * S_ + s) * D_) + row) * D_ + c16 * 8);
    *(uint4v*)(Bs + row * 128 + sw) = vb;
  }
  __syncthreads();
  int wave = tid >> 6, lane = tid & 63;
  int l15 = lane & 15, lg = lane >> 4;
  f32x4 acc[2][8];
#pragma unroll
  for (int i = 0; i < 2; ++i)
#pragma unroll
    for (int j = 0; j < 8; ++j) acc[i][j] = (f32x4)(0.f);
#pragma unroll
  for (int kk = 0; kk < 4; ++kk) {
    int cc = kk * 4 + lg;  // 16B-chunk index within row
    short8 a[2], b[8];
#pragma unroll
    for (int i = 0; i < 2; ++i) {
      int row = wave * 32 + i * 16 + l15;
      a[i] = *(const short8*)(As + row * 128 + ((cc ^ (row & 7)) * 8));
    }
#pragma unroll
    for (int j = 0; j < 8; ++j) {
      int row = j * 16 + l15;
      b[j] = *(const short8*)(Bs + row * 128 + ((cc ^ (row & 7)) * 8));
    }
#pragma unroll
    for (int i = 0; i < 2; ++i)
#pragma unroll
      for (int j = 0; j < 8; ++j)
        acc[i][j] = __builtin_amdgcn_mfma_f32_16x16x32_bf16(a[i], b[j], acc[i][j], 0, 0, 0);
  }
#pragma unroll
  for (int i = 0; i < 2; ++i) {
#pragma unroll
    for (int rr = 0; rr < 4; ++rr) {
      int rloc = wave * 32 + i * 16 + lg * 4 + rr;  // D row = (lane>>4)*4+reg
      int b_g = bt * 128 + rloc;
      float rs = 0.f, rq = 0.f;
#pragma unroll
      for (int j = 0; j < 8; ++j) {
        float val = acc[i][j][rr];
        int o = j * 16 + l15;  // D col = lane&15
        se[(((size_t)b_g * H_ + h) * S_ + s) * D_ + o] = f2bf(val);
        rs += val; rq += val * val;
      }
#pragma unroll
      for (int m = 1; m <= 8; m <<= 1) {
        rs += __shfl_xor(rs, m);
        rq += __shfl_xor(rq, m);
      }
      if (l15 == 0) {
        ssum[((size_t)s * N_ + b_g) * H_ + h] = rs;
        ssq[((size_t)s * N_ + b_g) * H_ + h] = rq;
      }
    }
  }
}

// ---------------------------------------------------------------------------
// K2: LN1 stats finalize -> mean,rstd per (b,h)
// ---------------------------------------------------------------------------
__global__ __launch_bounds__(256) void k_finalize(const float* __restrict__ ssum,
                                                  const float* __restrict__ ssq,
                                                  float* __restrict__ mr) {
  int t = blockIdx.x * 256 + threadIdx.x;  // N*H = 16384
  float s1 = 0.f, s2 = 0.f;
#pragma unroll
  for (int s = 0; s < S_; ++s) {
    s1 += ssum[(size_t)s * (N_ * H_) + t];
    s2 += ssq[(size_t)s * (N_ * H_) + t];
  }
  float mu = s1 * (1.f / 2048.f);
  float var = s2 * (1.f / 2048.f) - mu * mu;
  mr[t * 2] = mu;
  mr[t * 2 + 1] = rsqrtf(var + EPS_);
}

// ---------------------------------------------------------------------------
// K3: out_part[sh] = sum over 8 s of [diff | act(LN1(se))] @ Wj[h,s]
// M-tile 128(b) x N=128(o), K=2048 in 16 chunks of 128; LN1+PReLU fused into
// odd-chunk staging. acc stays in registers across the whole K loop.
// ---------------------------------------------------------------------------
__global__ __launch_bounds__(256) void k_gemm2(const ushortT* __restrict__ diff,
                                               const ushortT* __restrict__ se,
                                               const ushortT* __restrict__ Wjt,
                                               const float* __restrict__ mr,
                                               const float* __restrict__ ln1w,
                                               const float* __restrict__ ln1b,
                                               const float* __restrict__ pa1,
                                               float* __restrict__ outp) {
  int bt = blockIdx.x, sh = blockIdx.y, h = blockIdx.z;
  __shared__ ushortT As[128 * 128];
  __shared__ ushortT Bs[128 * 128];
  int tid = threadIdx.x;
  float mu_r[8], rs_r[8];
#pragma unroll
  for (int i = 0; i < 8; ++i) {
    int row = (tid >> 4) + 16 * i;
    int b_g = bt * 128 + row;
    mu_r[i] = mr[((size_t)b_g * H_ + h) * 2];
    rs_r[i] = mr[((size_t)b_g * H_ + h) * 2 + 1];
  }
  float a1 = pa1[0];
  int wave = tid >> 6, lane = tid & 63;
  int l15 = lane & 15, lg = lane >> 4;
  f32x4 acc[2][8];
#pragma unroll
  for (int i = 0; i < 2; ++i)
#pragma unroll
    for (int j = 0; j < 8; ++j) acc[i][j] = (f32x4)(0.f);

  for (int kc = 0; kc < 16; ++kc) {
    int s = sh * 8 + (kc >> 1);
    int odd = kc & 1;
#pragma unroll
    for (int i = 0; i < 8; ++i) {
      int c = tid + 256 * i;
      int row = c >> 4, c16 = c & 15;
      int sw = ((c16 ^ (row & 7)) * 8);
      uint4v vb = *(const uint4v*)(Wjt + (size_t)(h * D_ + row) * (S_ * 256) + s * 256 + odd * 128 + c16 * 8);
      *(uint4v*)(Bs + row * 128 + sw) = vb;
      if (!odd) {
        uint4v va = *(const uint4v*)(diff + (size_t)(bt * 128 + row) * (S_ * D_) + s * D_ + c16 * 8);
        *(uint4v*)(As + row * 128 + sw) = va;
      } else {
        ushort8 vs = *(const ushort8*)(se + (((size_t)(bt * 128 + row) * H_ + h) * S_ + s) * D_ + c16 * 8);
        float8 wv = *(const float8*)(ln1w + s * D_ + c16 * 8);
        float8 bv = *(const float8*)(ln1b + s * D_ + c16 * 8);
        float mu = mu_r[i], rstd = rs_r[i];
        ushort8 res;
#pragma unroll
        for (int e = 0; e < 8; ++e) {
          float f = bf2f(vs[e]);
          float y = (f - mu) * rstd;
          y = y * wv[e] + bv[e];
          y = (y >= 0.f) ? y : a1 * y;
          res[e] = f2bf(y);
        }
        *(ushort8*)(As + row * 128 + sw) = res;
      }
    }
    __syncthreads();
#pragma unroll
    for (int kk = 0; kk < 4; ++kk) {
      int cc = kk * 4 + lg;
      short8 a[2], b[8];
#pragma unroll
      for (int i = 0; i < 2; ++i) {
        int row = wave * 32 + i * 16 + l15;
        a[i] = *(const short8*)(As + row * 128 + ((cc ^ (row & 7)) * 8));
      }
#pragma unroll
      for (int j = 0; j < 8; ++j) {
        int row = j * 16 + l15;
        b[j] = *(const short8*)(Bs + row * 128 + ((cc ^ (row & 7)) * 8));
      }
#pragma unroll
      for (int i = 0; i < 2; ++i)
#pragma unroll
        for (int j = 0; j < 8; ++j)
          acc[i][j] = __builtin_amdgcn_mfma_f32_16x16x32_bf16(a[i], b[j], acc[i][j], 0, 0, 0);
    }
    __syncthreads();
  }
#pragma unroll
  for (int i = 0; i < 2; ++i)
#pragma unroll
    for (int rr = 0; rr < 4; ++rr) {
      int rloc = wave * 32 + i * 16 + lg * 4 + rr;
      int b_g = bt * 128 + rloc;
#pragma unroll
      for (int j = 0; j < 8; ++j) {
        int o = j * 16 + l15;
        outp[(size_t)sh * (N_ * H_ * D_) + (size_t)b_g * (H_ * D_) + h * D_ + o] = acc[i][j][rr];
      }
    }
}

// ---------------------------------------------------------------------------
// K4: combine 2 K-partials, LN2 over (H,D)=1024 per b, PReLU, write f32 out
// ---------------------------------------------------------------------------
__global__ __launch_bounds__(256) void k_ln2(const float* __restrict__ outp,
                                             const float* __restrict__ ln2w,
                                             const float* __restrict__ ln2b,
                                             const float* __restrict__ pa2,
                                             float* __restrict__ out) {
  int b = blockIdx.x, t = threadIdx.x;
  __shared__ float red[8];
  __shared__ float stats[2];
  const f32x4* p0 = (const f32x4*)(outp + (size_t)b * 1024);
  const f32x4* p1 = (const f32x4*)(outp + (size_t)N_ * 1024 + (size_t)b * 1024);
  f32x4 v = p0[t] + p1[t];
  float s1 = v[0] + v[1] + v[2] + v[3];
  float s2 = v[0] * v[0] + v[1] * v[1] + v[2] * v[2] + v[3] * v[3];
#pragma unroll
  for (int m = 1; m <= 32; m <<= 1) {
    s1 += __shfl_xor(s1, m);
    s2 += __shfl_xor(s2, m);
  }
  int wave = t >> 6, lane = t & 63;
  if (lane == 0) { red[wave] = s1; red[4 + wave] = s2; }
  __syncthreads();
  if (t == 0) {
    float S = red[0] + red[1] + red[2] + red[3];
    float Q = red[4] + red[5] + red[6] + red[7];
    float mu = S * (1.f / 1024.f);
    float var = Q * (1.f / 1024.f) - mu * mu;
    stats[0] = mu; stats[1] = rsqrtf(var + EPS_);
  }
  __syncthreads();
  float mu = stats[0], rstd = stats[1];
  float a2 = pa2[0];
  f32x4 wv = *((const f32x4*)ln2w + t);
  f32x4 bv = *((const f32x4*)ln2b + t);
  f32x4 r;
#pragma unroll
  for (int e = 0; e < 4; ++e) {
    float y = (v[e] - mu) * rstd * wv[e] + bv[e];
    r[e] = (y >= 0.f) ? y : a2 * y;
  }
  *((f32x4*)(out + (size_t)b * 1024) + t) = r;
}

// ---------------------------------------------------------------------------
extern "C" void kernel_launch(void* const* d_in, const int* in_sizes, int n_in,
                              void* d_out, int out_size, void* d_ws, size_t ws_size,
                              hipStream_t stream) {
  const float* x    = (const float*)d_in[0];
  const float* Wi   = (const float*)d_in[1];
  const float* Wj   = (const float*)d_in[2];
  const float* ln1w = (const float*)d_in[3];
  const float* ln1b = (const float*)d_in[4];
  const float* pa1  = (const float*)d_in[5];
  const float* ln2w = (const float*)d_in[6];
  const float* ln2b = (const float*)d_in[7];
  const float* pa2  = (const float*)d_in[8];
  char* ws = (char*)d_ws;
  // ws layout (bytes):
  ushortT* enc  = (ushortT*)(ws + 0);          //  8 MB  [N][S][D] bf16
  ushortT* diff = (ushortT*)(ws + 8388608);    //  8 MB  [N][S][D] bf16
  ushortT* Wit  = (ushortT*)(ws + 16777216);   //  4 MB  [H][S][o][d] bf16
  ushortT* Wjt  = (ushortT*)(ws + 20971520);   //  8 MB  [H][o][S*256] bf16
  ushortT* se   = (ushortT*)(ws + 29360128);   // 64 MB  [N][H][S][D] bf16
  float*   ssum = (float*)(ws + 96468992);     //  1 MB  [S][N][H]
  float*   ssq  = (float*)(ws + 97517568);     //  1 MB  [S][N][H]
  float*   mr   = (float*)(ws + 98566144);     // 128 KB [N][H][2]
  float*   outp = (float*)(ws + 98697216);     // 16 MB  [2][N][H][D]
  float*   out  = (float*)d_out;

  hipLaunchKernelGGL(k_prep, dim3(1024), dim3(256), 0, stream, x, enc, diff);
  hipLaunchKernelGGL(k_castWi, dim3(128), dim3(256), 0, stream, Wi, Wit);
  hipLaunchKernelGGL(k_castWj, dim3(128), dim3(256), 0, stream, Wj, Wjt);
  hipLaunchKernelGGL(k_gemm1, dim3(16, 16, 8), dim3(256), 0, stream, enc, Wit, se, ssum, ssq);
  hipLaunchKernelGGL(k_finalize, dim3(64), dim3(256), 0, stream, ssum, ssq, mr);
  hipLaunchKernelGGL(k_gemm2, dim3(16, 2, 8), dim3(256), 0, stream, diff, se, Wjt, mr,
                     ln1w, ln1b, pa1, outp);
  hipLaunchKernelGGL(k_ln2, dim3(2048), dim3(256), 0, stream, outp, ln2w, ln2b, pa2, out);
}

// Round 2
// 217.703 us; speedup vs baseline: 1.1985x; 1.1985x over previous
//
#include <hip/hip_runtime.h>

#define N_ 2048
#define S_ 16
#define D_ 128
#define H_ 8
#define EPS_ 1e-5f

typedef unsigned short ushortT;
typedef unsigned int uint32;
typedef __attribute__((ext_vector_type(8))) short short8;
typedef __attribute__((ext_vector_type(8))) unsigned short ushort8;
typedef __attribute__((ext_vector_type(4))) float f32x4;
typedef __attribute__((ext_vector_type(4))) unsigned int uint4v;
typedef __attribute__((ext_vector_type(8))) float float8;

__device__ __forceinline__ ushortT f2bf(float f) {
  union { float f; uint32 u; } c; c.f = f;
  uint32 u = c.u;
  u = (u + 0x7FFFu + ((u >> 16) & 1u)) >> 16;  // RNE
  return (ushortT)u;
}
__device__ __forceinline__ float bf2f(ushortT b) {
  union { uint32 u; float f; } c; c.u = ((uint32)b) << 16;
  return c.f;
}

// ---------------------------------------------------------------------------
// K0: per-(n,d) column: stable-descending ranks over S=16, diff + enc (bf16)
// ---------------------------------------------------------------------------
__global__ __launch_bounds__(256) void k_prep(const float* __restrict__ x,
                                              ushortT* __restrict__ enc,
                                              ushortT* __restrict__ diff) {
  int g = blockIdx.x * 256 + threadIdx.x;  // N*D = 262144 threads
  int n = g >> 7, d = g & 127;
  const float* xp = x + (size_t)n * (S_ * D_) + d;
  float v[S_];
#pragma unroll
  for (int s = 0; s < S_; ++s) v[s] = xp[s * D_];
  int r[S_];
#pragma unroll
  for (int i = 0; i < S_; ++i) {
    int ri = 0;
#pragma unroll
    for (int j = 0; j < S_; ++j)
      ri += ((v[j] > v[i]) || (v[j] == v[i] && j < i)) ? 1 : 0;
    r[i] = ri;
  }
  float xs[S_ + 1];
#pragma unroll
  for (int s = 0; s < S_; ++s) {
    float acc = 0.f;
#pragma unroll
    for (int i = 0; i < S_; ++i) acc += (r[i] == s) ? v[i] : 0.f;
    xs[s] = acc;
  }
  xs[S_] = 0.f;
  ushortT* ep = enc + (size_t)n * (S_ * D_) + d;
  ushortT* dp = diff + (size_t)n * (S_ * D_) + d;
#pragma unroll
  for (int s = 0; s < S_; ++s) {
    uint32 mm = 0;
#pragma unroll
    for (int i = 0; i < S_; ++i) mm |= (r[i] <= s) ? (1u << i) : 0u;
    ep[s * D_] = f2bf((float)mm * (1.f / 65536.f));
    dp[s * D_] = f2bf(xs[s] - xs[s + 1]);
  }
}

// ---------------------------------------------------------------------------
// K0b: Wi[h][s][d][o] f32 -> Wit[h][s][o][d] bf16
// ---------------------------------------------------------------------------
__global__ __launch_bounds__(256) void k_castWi(const float* __restrict__ Wi,
                                                ushortT* __restrict__ Wit) {
  __shared__ ushortT tile[D_ * 136];
  int hs = blockIdx.x;
  const float* src = Wi + (size_t)hs * D_ * D_;
  int t = threadIdx.x;
#pragma unroll 4
  for (int i = 0; i < 64; ++i) {
    int e = t + 256 * i;
    int dd = e >> 7, o = e & 127;
    tile[dd * 136 + o] = f2bf(src[e]);
  }
  __syncthreads();
  int o = t >> 1, dbase = (t & 1) * 64;
  ushortT* dst = Wit + ((size_t)hs * D_ + o) * D_ + dbase;
#pragma unroll
  for (int c = 0; c < 8; ++c) {
    uint4v pk;
#pragma unroll
    for (int q = 0; q < 4; ++q) {
      ushortT lo = tile[(dbase + c * 8 + q * 2) * 136 + o];
      ushortT hi = tile[(dbase + c * 8 + q * 2 + 1) * 136 + o];
      pk[q] = (uint32)lo | ((uint32)hi << 16);
    }
    *(uint4v*)(dst + c * 8) = pk;
  }
}

// ---------------------------------------------------------------------------
// K0c: Wj[h][s][dd][o] f32 -> Wjt[h][o][s*256+dd] bf16, in two dd-halves
// ---------------------------------------------------------------------------
__global__ __launch_bounds__(256) void k_castWj(const float* __restrict__ Wj,
                                                ushortT* __restrict__ Wjt) {
  __shared__ ushortT tile[128 * 136];
  int hs = blockIdx.x; int h = hs >> 4, s = hs & 15;
  const float* src = Wj + (size_t)hs * 256 * D_;
  int t = threadIdx.x;
  for (int half = 0; half < 2; ++half) {
#pragma unroll 4
    for (int i = 0; i < 64; ++i) {
      int e = t + 256 * i;
      int dd = e >> 7, o = e & 127;
      tile[dd * 136 + o] = f2bf(src[half * 16384 + e]);
    }
    __syncthreads();
    int o = t >> 1, db = (t & 1) * 64;
    ushortT* dst = Wjt + ((size_t)(h * D_ + o)) * (S_ * 256) + s * 256 + half * 128 + db;
#pragma unroll
    for (int c = 0; c < 8; ++c) {
      uint4v pk;
#pragma unroll
      for (int q = 0; q < 4; ++q) {
        ushortT lo = tile[(db + c * 8 + q * 2) * 136 + o];
        ushortT hi = tile[(db + c * 8 + q * 2 + 1) * 136 + o];
        pk[q] = (uint32)lo | ((uint32)hi << 16);
      }
      *(uint4v*)(dst + c * 8) = pk;
    }
    __syncthreads();
  }
}

// ---------------------------------------------------------------------------
// K1: se[b,h,s,:] = enc[b,s,:] @ Wi[h,s] ; per-(s,b,h) sum/sumsq partials.
// Epilogue: C transposed through LDS -> coalesced 16B se stores.
// ---------------------------------------------------------------------------
__global__ __launch_bounds__(256) void k_gemm1(const ushortT* __restrict__ enc,
                                               const ushortT* __restrict__ Wit,
                                               ushortT* __restrict__ se,
                                               float* __restrict__ ssum,
                                               float* __restrict__ ssq) {
  int bt = blockIdx.x, s = blockIdx.y, h = blockIdx.z;
  __shared__ ushortT As[128 * 128];
  __shared__ ushortT Bs[128 * 128];
  int tid = threadIdx.x;
#pragma unroll
  for (int i = 0; i < 8; ++i) {
    int c = tid + 256 * i;
    int row = c >> 4, c16 = c & 15;
    int sw = ((c16 ^ (row & 7)) * 8);
    uint4v va = *(const uint4v*)(enc + (size_t)(bt * 128 + row) * (S_ * D_) + s * D_ + c16 * 8);
    *(uint4v*)(As + row * 128 + sw) = va;
    uint4v vb = *(const uint4v*)(Wit + ((size_t)((h * S_ + s) * D_) + row) * D_ + c16 * 8);
    *(uint4v*)(Bs + row * 128 + sw) = vb;
  }
  __syncthreads();
  int wave = tid >> 6, lane = tid & 63;
  int l15 = lane & 15, lg = lane >> 4;
  f32x4 acc[2][8];
#pragma unroll
  for (int i = 0; i < 2; ++i)
#pragma unroll
    for (int j = 0; j < 8; ++j) acc[i][j] = (f32x4)(0.f);
#pragma unroll
  for (int kk = 0; kk < 4; ++kk) {
    int cc = kk * 4 + lg;
    short8 a[2], b[8];
#pragma unroll
    for (int i = 0; i < 2; ++i) {
      int row = wave * 32 + i * 16 + l15;
      a[i] = *(const short8*)(As + row * 128 + ((cc ^ (row & 7)) * 8));
    }
#pragma unroll
    for (int j = 0; j < 8; ++j) {
      int row = j * 16 + l15;
      b[j] = *(const short8*)(Bs + row * 128 + ((cc ^ (row & 7)) * 8));
    }
#pragma unroll
    for (int i = 0; i < 2; ++i)
#pragma unroll
      for (int j = 0; j < 8; ++j)
        acc[i][j] = __builtin_amdgcn_mfma_f32_16x16x32_bf16(a[i], b[j], acc[i][j], 0, 0, 0);
  }
  // stats partials from registers
#pragma unroll
  for (int i = 0; i < 2; ++i) {
#pragma unroll
    for (int rr = 0; rr < 4; ++rr) {
      int rloc = wave * 32 + i * 16 + lg * 4 + rr;
      int b_g = bt * 128 + rloc;
      float rs = 0.f, rq = 0.f;
#pragma unroll
      for (int j = 0; j < 8; ++j) {
        float val = acc[i][j][rr];
        rs += val; rq += val * val;
      }
#pragma unroll
      for (int m = 1; m <= 8; m <<= 1) {
        rs += __shfl_xor(rs, m);
        rq += __shfl_xor(rq, m);
      }
      if (l15 == 0) {
        ssum[((size_t)s * N_ + b_g) * H_ + h] = rs;
        ssq[((size_t)s * N_ + b_g) * H_ + h] = rq;
      }
    }
  }
  // transpose C through LDS (swizzled), then coalesced 16B stores
  __syncthreads();
#pragma unroll
  for (int i = 0; i < 2; ++i)
#pragma unroll
    for (int rr = 0; rr < 4; ++rr) {
      int row = wave * 32 + i * 16 + lg * 4 + rr;
      int sw = (row & 7) << 3;
#pragma unroll
      for (int j = 0; j < 8; ++j) {
        int o = j * 16 + l15;
        As[row * 128 + (o ^ sw)] = f2bf(acc[i][j][rr]);
      }
    }
  __syncthreads();
#pragma unroll
  for (int p = 0; p < 2; ++p) {
    int row = p * 64 + (tid >> 2);
    int sw = (row & 7) << 3;
    int b_g = bt * 128 + row;
    ushortT* dst = se + (((size_t)b_g * H_ + h) * S_ + s) * D_;
#pragma unroll
    for (int q = 0; q < 4; ++q) {
      int o0 = (q * 4 + (tid & 3)) * 8;
      *(uint4v*)(dst + o0) = *(const uint4v*)(As + row * 128 + (o0 ^ sw));
    }
  }
}

// ---------------------------------------------------------------------------
// K2: LN1 stats finalize -> mean,rstd per (b,h)
// ---------------------------------------------------------------------------
__global__ __launch_bounds__(256) void k_finalize(const float* __restrict__ ssum,
                                                  const float* __restrict__ ssq,
                                                  float* __restrict__ mr) {
  int t = blockIdx.x * 256 + threadIdx.x;  // N*H = 16384
  float s1 = 0.f, s2 = 0.f;
#pragma unroll
  for (int s = 0; s < S_; ++s) {
    s1 += ssum[(size_t)s * (N_ * H_) + t];
    s2 += ssq[(size_t)s * (N_ * H_) + t];
  }
  float mu = s1 * (1.f / 2048.f);
  float var = s2 * (1.f / 2048.f) - mu * mu;
  mr[t * 2] = mu;
  mr[t * 2 + 1] = rsqrtf(var + EPS_);
}

// ---------------------------------------------------------------------------
// K2b: in-place LN1 + PReLU over se  (se[b,h,s,d])
// ---------------------------------------------------------------------------
__global__ __launch_bounds__(256) void k_act(ushortT* __restrict__ se,
                                             const float* __restrict__ mr,
                                             const float* __restrict__ ln1w,
                                             const float* __restrict__ ln1b,
                                             const float* __restrict__ pa1) {
  int g = blockIdx.x * 256 + threadIdx.x;  // N*H*S*D/8 = 4,194,304 groups
  int d8 = g & 15, s = (g >> 4) & 15, bh = g >> 8;
  float mu = mr[bh * 2], rstd = mr[bh * 2 + 1];
  float a1 = pa1[0];
  ushort8 v = *(ushort8*)(se + (size_t)g * 8);
  float8 w = *(const float8*)(ln1w + s * D_ + d8 * 8);
  float8 bb = *(const float8*)(ln1b + s * D_ + d8 * 8);
  ushort8 r;
#pragma unroll
  for (int e = 0; e < 8; ++e) {
    float f = bf2f(v[e]);
    float y = (f - mu) * rstd * w[e] + bb[e];
    y = (y >= 0.f) ? y : a1 * y;
    r[e] = f2bf(y);
  }
  *(ushort8*)(se + (size_t)g * 8) = r;
}

// ---------------------------------------------------------------------------
// K3: out_part[sh] = sum over scount s of [diff | se_act] @ Wj[h,s]
// BK=64 chunks, 4 waves, 64x64 wave tiles, T14 async-stage pipeline.
// chunk c: s = s0 + (c>>2); part p=c&3: {diff lo, diff hi, se lo, se hi}
// ---------------------------------------------------------------------------
__global__ __launch_bounds__(256, 3) void k_gemm2(const ushortT* __restrict__ diff,
                                                  const ushortT* __restrict__ se,
                                                  const ushortT* __restrict__ Wjt,
                                                  float* __restrict__ outp,
                                                  int scount) {
  int bt = blockIdx.x, sh = blockIdx.y, h = blockIdx.z;
  int s0 = sh * scount;
  __shared__ ushortT As[128 * 64];
  __shared__ ushortT Bs[128 * 64];
  int tid = threadIdx.x;
  int c8 = tid & 7, trow = tid >> 3;               // trow 0..31
  int swst = ((c8 ^ (trow & 7)) * 8);              // store swizzle (row&7==trow&7)
  int wave = tid >> 6, lane = tid & 63;
  int l15 = lane & 15, lg = lane >> 4;
  int wm = wave >> 1, wn = wave & 1;

  uint32 aoff_d[4], aoff_s[4], boff[4];
#pragma unroll
  for (int i = 0; i < 4; ++i) {
    int row = i * 32 + trow;
    aoff_d[i] = (uint32)(bt * 128 + row) * (S_ * D_) + c8 * 8;
    aoff_s[i] = ((uint32)(bt * 128 + row) * H_ + h) * (S_ * D_) + c8 * 8;
    boff[i] = (uint32)(h * D_ + row) * (S_ * 256) + c8 * 8;
  }
  uint4v ra[4], rb[4];
  int nc = scount * 4;
  {  // prologue load chunk 0 (s=s0, p=0 -> diff lo)
    uint32 add = s0 * D_;
#pragma unroll
    for (int i = 0; i < 4; ++i) {
      ra[i] = *(const uint4v*)(diff + aoff_d[i] + add);
      rb[i] = *(const uint4v*)(Wjt + boff[i] + s0 * 256);
    }
  }
  f32x4 acc[4][4];
#pragma unroll
  for (int i = 0; i < 4; ++i)
#pragma unroll
    for (int j = 0; j < 4; ++j) acc[i][j] = (f32x4)(0.f);

  for (int c = 0; c < nc; ++c) {
    if (c) __syncthreads();
#pragma unroll
    for (int i = 0; i < 4; ++i) {
      int row = i * 32 + trow;
      *(uint4v*)(As + row * 64 + swst) = ra[i];
      *(uint4v*)(Bs + row * 64 + swst) = rb[i];
    }
    if (c + 1 < nc) {  // T14: issue next chunk loads; they fly during MFMA
      int cn = c + 1;
      int s = s0 + (cn >> 2), p = cn & 3;
      uint32 add = s * D_ + (p & 1) * 64;
      uint32 badd = s * 256 + p * 64;
#pragma unroll
      for (int i = 0; i < 4; ++i) {
        ra[i] = (p < 2) ? *(const uint4v*)(diff + aoff_d[i] + add)
                        : *(const uint4v*)(se + aoff_s[i] + add);
        rb[i] = *(const uint4v*)(Wjt + boff[i] + badd);
      }
    }
    __syncthreads();
#pragma unroll
    for (int kk = 0; kk < 2; ++kk) {
      int cc = kk * 4 + lg;
      short8 a[4], b[4];
#pragma unroll
      for (int i = 0; i < 4; ++i) {
        int row = wm * 64 + i * 16 + l15;
        a[i] = *(const short8*)(As + row * 64 + ((cc ^ (row & 7)) * 8));
      }
#pragma unroll
      for (int j = 0; j < 4; ++j) {
        int row = wn * 64 + j * 16 + l15;
        b[j] = *(const short8*)(Bs + row * 64 + ((cc ^ (row & 7)) * 8));
      }
#pragma unroll
      for (int i = 0; i < 4; ++i)
#pragma unroll
        for (int j = 0; j < 4; ++j)
          acc[i][j] = __builtin_amdgcn_mfma_f32_16x16x32_bf16(a[i], b[j], acc[i][j], 0, 0, 0);
    }
  }
#pragma unroll
  for (int i = 0; i < 4; ++i)
#pragma unroll
    for (int j = 0; j < 4; ++j)
#pragma unroll
      for (int rr = 0; rr < 4; ++rr) {
        int b_g = bt * 128 + wm * 64 + i * 16 + lg * 4 + rr;
        int o = wn * 64 + j * 16 + l15;
        outp[(((size_t)sh * N_ + b_g) * H_ + h) * D_ + o] = acc[i][j][rr];
      }
}

// ---------------------------------------------------------------------------
// K4: combine nsplit K-partials, LN2 over (H,D)=1024 per b, PReLU, f32 out
// ---------------------------------------------------------------------------
__global__ __launch_bounds__(256) void k_ln2(const float* __restrict__ outp,
                                             const float* __restrict__ ln2w,
                                             const float* __restrict__ ln2b,
                                             const float* __restrict__ pa2,
                                             float* __restrict__ out,
                                             int nsplit) {
  int b = blockIdx.x, t = threadIdx.x;
  __shared__ float red[8];
  __shared__ float stats[2];
  f32x4 v = (f32x4)(0.f);
  for (int p = 0; p < nsplit; ++p)
    v += *((const f32x4*)(outp + (size_t)p * (N_ * 1024) + (size_t)b * 1024) + t);
  float s1 = v[0] + v[1] + v[2] + v[3];
  float s2 = v[0] * v[0] + v[1] * v[1] + v[2] * v[2] + v[3] * v[3];
#pragma unroll
  for (int m = 1; m <= 32; m <<= 1) {
    s1 += __shfl_xor(s1, m);
    s2 += __shfl_xor(s2, m);
  }
  int wave = t >> 6, lane = t & 63;
  if (lane == 0) { red[wave] = s1; red[4 + wave] = s2; }
  __syncthreads();
  if (t == 0) {
    float S = red[0] + red[1] + red[2] + red[3];
    float Q = red[4] + red[5] + red[6] + red[7];
    float mu = S * (1.f / 1024.f);
    float var = Q * (1.f / 1024.f) - mu * mu;
    stats[0] = mu; stats[1] = rsqrtf(var + EPS_);
  }
  __syncthreads();
  float mu = stats[0], rstd = stats[1];
  float a2 = pa2[0];
  f32x4 wv = *((const f32x4*)ln2w + t);
  f32x4 bv = *((const f32x4*)ln2b + t);
  f32x4 r;
#pragma unroll
  for (int e = 0; e < 4; ++e) {
    float y = (v[e] - mu) * rstd * wv[e] + bv[e];
    r[e] = (y >= 0.f) ? y : a2 * y;
  }
  *((f32x4*)(out + (size_t)b * 1024) + t) = r;
}

// ---------------------------------------------------------------------------
extern "C" void kernel_launch(void* const* d_in, const int* in_sizes, int n_in,
                              void* d_out, int out_size, void* d_ws, size_t ws_size,
                              hipStream_t stream) {
  const float* x    = (const float*)d_in[0];
  const float* Wi   = (const float*)d_in[1];
  const float* Wj   = (const float*)d_in[2];
  const float* ln1w = (const float*)d_in[3];
  const float* ln1b = (const float*)d_in[4];
  const float* pa1  = (const float*)d_in[5];
  const float* ln2w = (const float*)d_in[6];
  const float* ln2b = (const float*)d_in[7];
  const float* pa2  = (const float*)d_in[8];
  char* ws = (char*)d_ws;
  // ws layout with liveness overlay:
  //   [0,64M)        se    (gemm1 -> act -> gemm2)
  //   [64M,72M)      diff  (prep -> gemm2)
  //   [72M,80M)      Wjt   (castWj -> gemm2)
  //   [80M, 80M+ns*8M) outp (gemm2 -> ln2), OVERLAYS:
  //       [80M,88M)   enc   (prep -> gemm1, dead before gemm2)
  //       [88M,92M)   Wit   (castWi -> gemm1, dead before gemm2)
  //       [92M,93M)   ssum  (gemm1 -> finalize)
  //       [93M,94M)   ssq
  //       [94M,94.1M) mr    (finalize -> act, dead before gemm2)
  ushortT* se   = (ushortT*)(ws + 0);
  ushortT* diff = (ushortT*)(ws + 67108864);
  ushortT* Wjt  = (ushortT*)(ws + 75497472);
  float*   outp = (float*)(ws + 83886080);
  ushortT* enc  = (ushortT*)(ws + 83886080);
  ushortT* Wit  = (ushortT*)(ws + 92274688);
  float*   ssum = (float*)(ws + 96468992);
  float*   ssq  = (float*)(ws + 97517568);
  float*   mr   = (float*)(ws + 98566144);
  float*   out  = (float*)d_out;

  // split-4 needs 83886080 + 4*8388608 = 117440512 bytes of ws
  int nsplit = (ws_size >= 117440512ull) ? 4 : 2;
  int scount = S_ / nsplit;

  hipLaunchKernelGGL(k_prep, dim3(1024), dim3(256), 0, stream, x, enc, diff);
  hipLaunchKernelGGL(k_castWi, dim3(128), dim3(256), 0, stream, Wi, Wit);
  hipLaunchKernelGGL(k_castWj, dim3(128), dim3(256), 0, stream, Wj, Wjt);
  hipLaunchKernelGGL(k_gemm1, dim3(16, 16, 8), dim3(256), 0, stream, enc, Wit, se, ssum, ssq);
  hipLaunchKernelGGL(k_finalize, dim3(64), dim3(256), 0, stream, ssum, ssq, mr);
  hipLaunchKernelGGL(k_act, dim3(16384), dim3(256), 0, stream, se, mr, ln1w, ln1b, pa1);
  hipLaunchKernelGGL(k_gemm2, dim3(16, nsplit, 8), dim3(256), 0, stream, diff, se, Wjt, outp, scount);
  hipLaunchKernelGGL(k_ln2, dim3(2048), dim3(256), 0, stream, outp, ln2w, ln2b, pa2, out, nsplit);
}

// Round 3
// 208.052 us; speedup vs baseline: 1.2541x; 1.0464x over previous
//
#include <hip/hip_runtime.h>

#define N_ 2048
#define S_ 16
#define D_ 128
#define H_ 8
#define EPS_ 1e-5f

typedef unsigned short ushortT;
typedef unsigned int uint32;
typedef __attribute__((ext_vector_type(8))) short short8;
typedef __attribute__((ext_vector_type(8))) unsigned short ushort8;
typedef __attribute__((ext_vector_type(4))) float f32x4;
typedef __attribute__((ext_vector_type(4))) unsigned int uint4v;
typedef __attribute__((ext_vector_type(8))) float float8;

__device__ __forceinline__ ushortT f2bf(float f) {
  union { float f; uint32 u; } c; c.f = f;
  uint32 u = c.u;
  u = (u + 0x7FFFu + ((u >> 16) & 1u)) >> 16;  // RNE
  return (ushortT)u;
}
__device__ __forceinline__ float bf2f(ushortT b) {
  union { uint32 u; float f; } c; c.u = ((uint32)b) << 16;
  return c.f;
}

// ---------------------------------------------------------------------------
// K0: per-(n,d) column: stable-descending ranks over S=16, diff + enc (bf16)
// ---------------------------------------------------------------------------
__global__ __launch_bounds__(256) void k_prep(const float* __restrict__ x,
                                              ushortT* __restrict__ enc,
                                              ushortT* __restrict__ diff) {
  int g = blockIdx.x * 256 + threadIdx.x;  // N*D = 262144 threads
  int n = g >> 7, d = g & 127;
  const float* xp = x + (size_t)n * (S_ * D_) + d;
  float v[S_];
#pragma unroll
  for (int s = 0; s < S_; ++s) v[s] = xp[s * D_];
  int r[S_];
#pragma unroll
  for (int i = 0; i < S_; ++i) {
    int ri = 0;
#pragma unroll
    for (int j = 0; j < S_; ++j)
      ri += ((v[j] > v[i]) || (v[j] == v[i] && j < i)) ? 1 : 0;
    r[i] = ri;
  }
  float xs[S_ + 1];
#pragma unroll
  for (int s = 0; s < S_; ++s) {
    float acc = 0.f;
#pragma unroll
    for (int i = 0; i < S_; ++i) acc += (r[i] == s) ? v[i] : 0.f;
    xs[s] = acc;
  }
  xs[S_] = 0.f;
  ushortT* ep = enc + (size_t)n * (S_ * D_) + d;
  ushortT* dp = diff + (size_t)n * (S_ * D_) + d;
#pragma unroll
  for (int s = 0; s < S_; ++s) {
    uint32 mm = 0;
#pragma unroll
    for (int i = 0; i < S_; ++i) mm |= (r[i] <= s) ? (1u << i) : 0u;
    ep[s * D_] = f2bf((float)mm * (1.f / 65536.f));
    dp[s * D_] = f2bf(xs[s] - xs[s + 1]);
  }
}

// ---------------------------------------------------------------------------
// K0b: merged weight casts.
//  blocks [0,128):   Wi[h][s][d][o] f32 -> Wit[h][s][o][d] bf16
//  blocks [128,256): Wj[h][s][dd][o] f32 -> Wjt[h][o][s*256+dd] bf16
// ---------------------------------------------------------------------------
__global__ __launch_bounds__(256) void k_castW(const float* __restrict__ Wi,
                                               const float* __restrict__ Wj,
                                               ushortT* __restrict__ Wit,
                                               ushortT* __restrict__ Wjt) {
  __shared__ ushortT tile[128 * 136];
  int bx = blockIdx.x;
  int t = threadIdx.x;
  if (bx < 128) {
    int hs = bx;
    const float* src = Wi + (size_t)hs * D_ * D_;
#pragma unroll 4
    for (int i = 0; i < 64; ++i) {
      int e = t + 256 * i;
      int dd = e >> 7, o = e & 127;
      tile[dd * 136 + o] = f2bf(src[e]);
    }
    __syncthreads();
    int o = t >> 1, dbase = (t & 1) * 64;
    ushortT* dst = Wit + ((size_t)hs * D_ + o) * D_ + dbase;
#pragma unroll
    for (int c = 0; c < 8; ++c) {
      uint4v pk;
#pragma unroll
      for (int q = 0; q < 4; ++q) {
        ushortT lo = tile[(dbase + c * 8 + q * 2) * 136 + o];
        ushortT hi = tile[(dbase + c * 8 + q * 2 + 1) * 136 + o];
        pk[q] = (uint32)lo | ((uint32)hi << 16);
      }
      *(uint4v*)(dst + c * 8) = pk;
    }
  } else {
    int hs = bx - 128; int h = hs >> 4, s = hs & 15;
    const float* src = Wj + (size_t)hs * 256 * D_;
    for (int half = 0; half < 2; ++half) {
      if (half) __syncthreads();
#pragma unroll 4
      for (int i = 0; i < 64; ++i) {
        int e = t + 256 * i;
        int dd = e >> 7, o = e & 127;
        tile[dd * 136 + o] = f2bf(src[half * 16384 + e]);
      }
      __syncthreads();
      int o = t >> 1, db = (t & 1) * 64;
      ushortT* dst = Wjt + ((size_t)(h * D_ + o)) * (S_ * 256) + s * 256 + half * 128 + db;
#pragma unroll
      for (int c = 0; c < 8; ++c) {
        uint4v pk;
#pragma unroll
        for (int q = 0; q < 4; ++q) {
          ushortT lo = tile[(db + c * 8 + q * 2) * 136 + o];
          ushortT hi = tile[(db + c * 8 + q * 2 + 1) * 136 + o];
          pk[q] = (uint32)lo | ((uint32)hi << 16);
        }
        *(uint4v*)(dst + c * 8) = pk;
      }
    }
  }
}

// ---------------------------------------------------------------------------
// K1: se[b,h,s,:] = enc[b,s,:] @ Wi[h,s] for 4 h per block; per-(s,b,h)
// sum/sumsq partials. A staged once, A-frags kept in registers across h;
// B register-prefetched (T14). C^T transposed through Bs -> coalesced stores.
// grid (16 bt, 16 s, 2 hp)
// ---------------------------------------------------------------------------
__global__ __launch_bounds__(256) void k_gemm1(const ushortT* __restrict__ enc,
                                               const ushortT* __restrict__ Wit,
                                               ushortT* __restrict__ se,
                                               float* __restrict__ ssum,
                                               float* __restrict__ ssq) {
  int bt = blockIdx.x, s = blockIdx.y, hp = blockIdx.z;
  int h0 = hp * 4;
  __shared__ ushortT As[128 * 128];
  __shared__ ushortT Bs[128 * 128];
  int tid = threadIdx.x;
  int c16 = tid & 15, prow = tid >> 4;  // staging: col-chunk 0..15, row 0..15
  int wave = tid >> 6, lane = tid & 63;
  int l15 = lane & 15, lg = lane >> 4;

  ushort8 rb[8];
  // prologue: stage A (enc tile) + load B(h0) to regs
#pragma unroll
  for (int i = 0; i < 8; ++i) {
    int row = prow + 16 * i;
    int sw = ((c16 ^ (row & 7)) * 8);
    ushort8 va = *(const ushort8*)(enc + (size_t)(bt * 128 + row) * (S_ * D_) + s * D_ + c16 * 8);
    *(ushort8*)(As + row * 128 + sw) = va;
    rb[i] = *(const ushort8*)(Wit + ((size_t)((h0 * S_ + s) * D_) + row) * D_ + c16 * 8);
  }
  __syncthreads();
  // preload A fragments (As free afterwards, Bs used as C^T scratch)
  short8 afr[4][2];
#pragma unroll
  for (int kk = 0; kk < 4; ++kk)
#pragma unroll
    for (int i = 0; i < 2; ++i) {
      int row = wave * 32 + i * 16 + l15;
      int cc = kk * 4 + lg;
      afr[kk][i] = *(const short8*)(As + row * 128 + ((cc ^ (row & 7)) * 8));
    }

  for (int hh = 0; hh < 4; ++hh) {
    int h = h0 + hh;
    if (hh) __syncthreads();  // B_a: prev-iter Bs readers done
#pragma unroll
    for (int i = 0; i < 8; ++i) {
      int row = prow + 16 * i;
      *(ushort8*)(Bs + row * 128 + ((c16 ^ (row & 7)) * 8)) = rb[i];
    }
    if (hh < 3) {  // prefetch next h's B while this h computes
#pragma unroll
      for (int i = 0; i < 8; ++i) {
        int row = prow + 16 * i;
        rb[i] = *(const ushort8*)(Wit + ((size_t)(((h + 1) * S_ + s) * D_) + row) * D_ + c16 * 8);
      }
    }
    __syncthreads();  // B_b
    f32x4 acc[2][8];
#pragma unroll
    for (int i = 0; i < 2; ++i)
#pragma unroll
      for (int j = 0; j < 8; ++j) acc[i][j] = (f32x4)(0.f);
#pragma unroll
    for (int kk = 0; kk < 4; ++kk) {
      int cc = kk * 4 + lg;
      short8 b[8];
#pragma unroll
      for (int j = 0; j < 8; ++j) {
        int row = j * 16 + l15;
        b[j] = *(const short8*)(Bs + row * 128 + ((cc ^ (row & 7)) * 8));
      }
#pragma unroll
      for (int i = 0; i < 2; ++i)
#pragma unroll
        for (int j = 0; j < 8; ++j)
          acc[i][j] = __builtin_amdgcn_mfma_f32_16x16x32_bf16(afr[kk][i], b[j], acc[i][j], 0, 0, 0);
    }
    // stats partials
#pragma unroll
    for (int i = 0; i < 2; ++i)
#pragma unroll
      for (int rr = 0; rr < 4; ++rr) {
        int rloc = wave * 32 + i * 16 + lg * 4 + rr;
        int b_g = bt * 128 + rloc;
        float rs = 0.f, rq = 0.f;
#pragma unroll
        for (int j = 0; j < 8; ++j) {
          float val = acc[i][j][rr];
          rs += val; rq += val * val;
        }
#pragma unroll
        for (int m = 1; m <= 8; m <<= 1) {
          rs += __shfl_xor(rs, m);
          rq += __shfl_xor(rq, m);
        }
        if (l15 == 0) {
          ssum[((size_t)s * N_ + b_g) * H_ + h] = rs;
          ssq[((size_t)s * N_ + b_g) * H_ + h] = rq;
        }
      }
    __syncthreads();  // B_c: all MFMA reads of Bs done
    // C^T into Bs (swizzled)
#pragma unroll
    for (int i = 0; i < 2; ++i)
#pragma unroll
      for (int rr = 0; rr < 4; ++rr) {
        int row = wave * 32 + i * 16 + lg * 4 + rr;
        int sw = (row & 7) << 3;
#pragma unroll
        for (int j = 0; j < 8; ++j) {
          int o = j * 16 + l15;
          Bs[row * 128 + (o ^ sw)] = f2bf(acc[i][j][rr]);
        }
      }
    __syncthreads();  // B_d
#pragma unroll
    for (int p = 0; p < 2; ++p) {
      int row = p * 64 + (tid >> 2);
      int sw = (row & 7) << 3;
      int b_g = bt * 128 + row;
      ushortT* dst = se + (((size_t)b_g * H_ + h) * S_ + s) * D_;
#pragma unroll
      for (int q = 0; q < 4; ++q) {
        int o0 = (q * 4 + (tid & 3)) * 8;
        *(uint4v*)(dst + o0) = *(const uint4v*)(Bs + row * 128 + (o0 ^ sw));
      }
    }
  }
}

// ---------------------------------------------------------------------------
// K2: LN1 stats finalize -> mean,rstd per (b,h)
// ---------------------------------------------------------------------------
__global__ __launch_bounds__(256) void k_finalize(const float* __restrict__ ssum,
                                                  const float* __restrict__ ssq,
                                                  float* __restrict__ mr) {
  int t = blockIdx.x * 256 + threadIdx.x;  // N*H = 16384
  float s1 = 0.f, s2 = 0.f;
#pragma unroll
  for (int s = 0; s < S_; ++s) {
    s1 += ssum[(size_t)s * (N_ * H_) + t];
    s2 += ssq[(size_t)s * (N_ * H_) + t];
  }
  float mu = s1 * (1.f / 2048.f);
  float var = s2 * (1.f / 2048.f) - mu * mu;
  mr[t * 2] = mu;
  mr[t * 2 + 1] = rsqrtf(var + EPS_);
}

// ---------------------------------------------------------------------------
// K3: out_part[sh] = sum over scount s of [diff | act(LN1(se))] @ Wj[h,s]
// LN1+PReLU fused into se-chunk staging (reg->LDS). BK=64, 4 waves,
// 64x64 wave tiles, T14 async-stage pipeline.
// chunk c: s = s0 + (c>>2); part p=c&3: {diff lo, diff hi, se lo, se hi}
// ---------------------------------------------------------------------------
__global__ __launch_bounds__(256, 3) void k_gemm2(const ushortT* __restrict__ diff,
                                                  const ushortT* __restrict__ se,
                                                  const ushortT* __restrict__ Wjt,
                                                  const float* __restrict__ mr,
                                                  const float* __restrict__ ln1w,
                                                  const float* __restrict__ ln1b,
                                                  const float* __restrict__ pa1,
                                                  float* __restrict__ outp,
                                                  int scount) {
  int bt = blockIdx.x, sh = blockIdx.y, h = blockIdx.z;
  int s0 = sh * scount;
  __shared__ ushortT As[128 * 64];
  __shared__ ushortT Bs[128 * 64];
  int tid = threadIdx.x;
  int c8 = tid & 7, trow = tid >> 3;               // trow 0..31
  int swst = ((c8 ^ (trow & 7)) * 8);              // store swizzle
  int wave = tid >> 6, lane = tid & 63;
  int l15 = lane & 15, lg = lane >> 4;
  int wm = wave >> 1, wn = wave & 1;
  float a1 = pa1[0];

  float mu_r[4], rs_r[4];
  uint32 aoff_d[4], aoff_s[4], boff[4];
#pragma unroll
  for (int i = 0; i < 4; ++i) {
    int row = i * 32 + trow;
    int b_g = bt * 128 + row;
    mu_r[i] = mr[((size_t)b_g * H_ + h) * 2];
    rs_r[i] = mr[((size_t)b_g * H_ + h) * 2 + 1];
    aoff_d[i] = (uint32)b_g * (S_ * D_) + c8 * 8;
    aoff_s[i] = ((uint32)b_g * H_ + h) * (S_ * D_) + c8 * 8;
    boff[i] = (uint32)(h * D_ + row) * (S_ * 256) + c8 * 8;
  }
  ushort8 ra[4], rb[4];
  int nc = scount * 4;
  {  // prologue load chunk 0 (s=s0, p=0 -> diff lo)
    uint32 add = s0 * D_;
#pragma unroll
    for (int i = 0; i < 4; ++i) {
      ra[i] = *(const ushort8*)(diff + aoff_d[i] + add);
      rb[i] = *(const ushort8*)(Wjt + boff[i] + s0 * 256);
    }
  }
  f32x4 acc[4][4];
#pragma unroll
  for (int i = 0; i < 4; ++i)
#pragma unroll
    for (int j = 0; j < 4; ++j) acc[i][j] = (f32x4)(0.f);

  for (int c = 0; c < nc; ++c) {
    int p = c & 3, s = s0 + (c >> 2);
    if (c) __syncthreads();
    if (p >= 2) {  // fused LN1 + PReLU on the se chunk
      float8 w8 = *(const float8*)(ln1w + s * D_ + (p & 1) * 64 + c8 * 8);
      float8 b8 = *(const float8*)(ln1b + s * D_ + (p & 1) * 64 + c8 * 8);
#pragma unroll
      for (int i = 0; i < 4; ++i) {
        ushort8 v = ra[i];
#pragma unroll
        for (int e = 0; e < 8; ++e) {
          float f = bf2f(v[e]);
          float y = (f - mu_r[i]) * rs_r[i] * w8[e] + b8[e];
          y = (y >= 0.f) ? y : a1 * y;
          v[e] = f2bf(y);
        }
        ra[i] = v;
      }
    }
#pragma unroll
    for (int i = 0; i < 4; ++i) {
      int row = i * 32 + trow;
      *(ushort8*)(As + row * 64 + swst) = ra[i];
      *(ushort8*)(Bs + row * 64 + swst) = rb[i];
    }
    if (c + 1 < nc) {  // T14: issue next chunk loads; they fly during MFMA
      int cn = c + 1;
      int sn = s0 + (cn >> 2), pn = cn & 3;
      uint32 add = sn * D_ + (pn & 1) * 64;
      uint32 badd = sn * 256 + pn * 64;
#pragma unroll
      for (int i = 0; i < 4; ++i) {
        ra[i] = (pn < 2) ? *(const ushort8*)(diff + aoff_d[i] + add)
                         : *(const ushort8*)(se + aoff_s[i] + add);
        rb[i] = *(const ushort8*)(Wjt + boff[i] + badd);
      }
    }
    __syncthreads();
#pragma unroll
    for (int kk = 0; kk < 2; ++kk) {
      int cc = kk * 4 + lg;
      short8 a[4], b[4];
#pragma unroll
      for (int i = 0; i < 4; ++i) {
        int row = wm * 64 + i * 16 + l15;
        a[i] = *(const short8*)(As + row * 64 + ((cc ^ (row & 7)) * 8));
      }
#pragma unroll
      for (int j = 0; j < 4; ++j) {
        int row = wn * 64 + j * 16 + l15;
        b[j] = *(const short8*)(Bs + row * 64 + ((cc ^ (row & 7)) * 8));
      }
#pragma unroll
      for (int i = 0; i < 4; ++i)
#pragma unroll
        for (int j = 0; j < 4; ++j)
          acc[i][j] = __builtin_amdgcn_mfma_f32_16x16x32_bf16(a[i], b[j], acc[i][j], 0, 0, 0);
    }
  }
#pragma unroll
  for (int i = 0; i < 4; ++i)
#pragma unroll
    for (int j = 0; j < 4; ++j)
#pragma unroll
      for (int rr = 0; rr < 4; ++rr) {
        int b_g = bt * 128 + wm * 64 + i * 16 + lg * 4 + rr;
        int o = wn * 64 + j * 16 + l15;
        outp[(((size_t)sh * N_ + b_g) * H_ + h) * D_ + o] = acc[i][j][rr];
      }
}

// ---------------------------------------------------------------------------
// K4: combine nsplit K-partials, LN2 over (H,D)=1024 per b, PReLU, f32 out
// ---------------------------------------------------------------------------
__global__ __launch_bounds__(256) void k_ln2(const float* __restrict__ outp,
                                             const float* __restrict__ ln2w,
                                             const float* __restrict__ ln2b,
                                             const float* __restrict__ pa2,
                                             float* __restrict__ out,
                                             int nsplit) {
  int b = blockIdx.x, t = threadIdx.x;
  __shared__ float red[8];
  __shared__ float stats[2];
  f32x4 v = (f32x4)(0.f);
  for (int p = 0; p < nsplit; ++p)
    v += *((const f32x4*)(outp + (size_t)p * (N_ * 1024) + (size_t)b * 1024) + t);
  float s1 = v[0] + v[1] + v[2] + v[3];
  float s2 = v[0] * v[0] + v[1] * v[1] + v[2] * v[2] + v[3] * v[3];
#pragma unroll
  for (int m = 1; m <= 32; m <<= 1) {
    s1 += __shfl_xor(s1, m);
    s2 += __shfl_xor(s2, m);
  }
  int wave = t >> 6, lane = t & 63;
  if (lane == 0) { red[wave] = s1; red[4 + wave] = s2; }
  __syncthreads();
  if (t == 0) {
    float S = red[0] + red[1] + red[2] + red[3];
    float Q = red[4] + red[5] + red[6] + red[7];
    float mu = S * (1.f / 1024.f);
    float var = Q * (1.f / 1024.f) - mu * mu;
    stats[0] = mu; stats[1] = rsqrtf(var + EPS_);
  }
  __syncthreads();
  float mu = stats[0], rstd = stats[1];
  float a2 = pa2[0];
  f32x4 wv = *((const f32x4*)ln2w + t);
  f32x4 bv = *((const f32x4*)ln2b + t);
  f32x4 r;
#pragma unroll
  for (int e = 0; e < 4; ++e) {
    float y = (v[e] - mu) * rstd * wv[e] + bv[e];
    r[e] = (y >= 0.f) ? y : a2 * y;
  }
  *((f32x4*)(out + (size_t)b * 1024) + t) = r;
}

// ---------------------------------------------------------------------------
extern "C" void kernel_launch(void* const* d_in, const int* in_sizes, int n_in,
                              void* d_out, int out_size, void* d_ws, size_t ws_size,
                              hipStream_t stream) {
  const float* x    = (const float*)d_in[0];
  const float* Wi   = (const float*)d_in[1];
  const float* Wj   = (const float*)d_in[2];
  const float* ln1w = (const float*)d_in[3];
  const float* ln1b = (const float*)d_in[4];
  const float* pa1  = (const float*)d_in[5];
  const float* ln2w = (const float*)d_in[6];
  const float* ln2b = (const float*)d_in[7];
  const float* pa2  = (const float*)d_in[8];
  char* ws = (char*)d_ws;
  // ws layout with liveness overlay:
  //   [0,64M)          se    (gemm1 -> gemm2)
  //   [64M,72M)        diff  (prep -> gemm2)
  //   [72M,80M)        Wjt   (castW -> gemm2)
  //   [80M,80M+ns*8M)  outp  (gemm2 -> ln2), OVERLAYS (dead before gemm2):
  //       [80M,88M)     enc   (prep -> gemm1)
  //       [88M,92M)     Wit   (castW -> gemm1)
  //       [92M,93M)     ssum  (gemm1 -> finalize)
  //       [93M,94M)     ssq
  //   [80M+ns*8M, +128K) mr   (finalize -> gemm2; must NOT overlay outp)
  ushortT* se   = (ushortT*)(ws + 0);
  ushortT* diff = (ushortT*)(ws + 67108864);
  ushortT* Wjt  = (ushortT*)(ws + 75497472);
  float*   outp = (float*)(ws + 83886080);
  ushortT* enc  = (ushortT*)(ws + 83886080);
  ushortT* Wit  = (ushortT*)(ws + 92274688);
  float*   ssum = (float*)(ws + 96468992);
  float*   ssq  = (float*)(ws + 97517568);
  float*   out  = (float*)d_out;

  // split-4 needs 80M + 4*8M (outp) + 128K (mr) = 117571584 bytes
  int nsplit = (ws_size >= 117571584ull) ? 4 : 2;
  int scount = S_ / nsplit;
  float* mr = (float*)(ws + 83886080 + (size_t)nsplit * 8388608);

  hipLaunchKernelGGL(k_prep, dim3(1024), dim3(256), 0, stream, x, enc, diff);
  hipLaunchKernelGGL(k_castW, dim3(256), dim3(256), 0, stream, Wi, Wj, Wit, Wjt);
  hipLaunchKernelGGL(k_gemm1, dim3(16, 16, 2), dim3(256), 0, stream, enc, Wit, se, ssum, ssq);
  hipLaunchKernelGGL(k_finalize, dim3(64), dim3(256), 0, stream, ssum, ssq, mr);
  hipLaunchKernelGGL(k_gemm2, dim3(16, nsplit, 8), dim3(256), 0, stream, diff, se, Wjt, mr,
                     ln1w, ln1b, pa1, outp, scount);
  hipLaunchKernelGGL(k_ln2, dim3(2048), dim3(256), 0, stream, outp, ln2w, ln2b, pa2, out, nsplit);
}

// Round 4
// 196.087 us; speedup vs baseline: 1.3306x; 1.0610x over previous
//
#include <hip/hip_runtime.h>

#define N_ 2048
#define S_ 16
#define D_ 128
#define H_ 8
#define EPS_ 1e-5f

typedef unsigned short ushortT;
typedef unsigned int uint32;
typedef __attribute__((ext_vector_type(8))) short short8;
typedef __attribute__((ext_vector_type(8))) unsigned short ushort8;
typedef __attribute__((ext_vector_type(4))) float f32x4;
typedef __attribute__((ext_vector_type(4))) unsigned int uint4v;
typedef __attribute__((ext_vector_type(8))) float float8;

__device__ __forceinline__ ushortT f2bf(float f) {
  union { float f; uint32 u; } c; c.f = f;
  uint32 u = c.u;
  u = (u + 0x7FFFu + ((u >> 16) & 1u)) >> 16;  // RNE
  return (ushortT)u;
}
__device__ __forceinline__ float bf2f(ushortT b) {
  union { uint32 u; float f; } c; c.u = ((uint32)b) << 16;
  return c.f;
}

// ---------------------------------------------------------------------------
// K0: per-(n,d) column: stable-descending ranks over S=16.
// enc -> [n][s][d] (normal). diff -> diff_sw: glds-linear swizzled tiles
// [bt][s][half][1024 q][8 e] where q = r*8 + (c8 ^ (r&7)), r=n&127.
// ---------------------------------------------------------------------------
__global__ __launch_bounds__(256) void k_prep(const float* __restrict__ x,
                                              ushortT* __restrict__ enc,
                                              ushortT* __restrict__ diff_sw) {
  int g = blockIdx.x * 256 + threadIdx.x;  // N*D = 262144 threads
  int n = g >> 7, d = g & 127;
  const float* xp = x + (size_t)n * (S_ * D_) + d;
  float v[S_];
#pragma unroll
  for (int s = 0; s < S_; ++s) v[s] = xp[s * D_];
  int r[S_];
#pragma unroll
  for (int i = 0; i < S_; ++i) {
    int ri = 0;
#pragma unroll
    for (int j = 0; j < S_; ++j)
      ri += ((v[j] > v[i]) || (v[j] == v[i] && j < i)) ? 1 : 0;
    r[i] = ri;
  }
  float xs[S_ + 1];
#pragma unroll
  for (int s = 0; s < S_; ++s) {
    float acc = 0.f;
#pragma unroll
    for (int i = 0; i < S_; ++i) acc += (r[i] == s) ? v[i] : 0.f;
    xs[s] = acc;
  }
  xs[S_] = 0.f;
  ushortT* ep = enc + (size_t)n * (S_ * D_) + d;
  // diff_sw addressing
  int btq = n >> 7, rr = n & 127, pp = d >> 6, c8p = (d >> 3) & 7, ee = d & 7;
  int q = rr * 8 + (c8p ^ (rr & 7));
#pragma unroll
  for (int s = 0; s < S_; ++s) {
    uint32 mm = 0;
#pragma unroll
    for (int i = 0; i < S_; ++i) mm |= (r[i] <= s) ? (1u << i) : 0u;
    ep[s * D_] = f2bf((float)mm * (1.f / 65536.f));
    size_t idx = ((((size_t)(btq * 16 + s) * 2 + pp) * 1024) + q) * 8 + ee;
    diff_sw[idx] = f2bf(xs[s] - xs[s + 1]);
  }
}

// ---------------------------------------------------------------------------
// K0b: merged weight casts.
//  blocks [0,128):   Wi[h][s][d][o] f32 -> Wit[h][s][o][d] bf16 (linear)
//  blocks [128,256): Wj[h][s][dd][o] f32 -> Wjt_sw[h][s][part][q][e] bf16
//    part = dd>>6 (0,1=diff-k, 2,3=se-k); q = o*8 + (c8 ^ (o&7)); glds-linear.
// ---------------------------------------------------------------------------
__global__ __launch_bounds__(256) void k_castW(const float* __restrict__ Wi,
                                               const float* __restrict__ Wj,
                                               ushortT* __restrict__ Wit,
                                               ushortT* __restrict__ Wjt_sw) {
  __shared__ ushortT tile[128 * 136];
  int bx = blockIdx.x;
  int t = threadIdx.x;
  if (bx < 128) {
    int hs = bx;
    const float* src = Wi + (size_t)hs * D_ * D_;
#pragma unroll 4
    for (int i = 0; i < 64; ++i) {
      int e = t + 256 * i;
      int dd = e >> 7, o = e & 127;
      tile[dd * 136 + o] = f2bf(src[e]);
    }
    __syncthreads();
    int o = t >> 1, dbase = (t & 1) * 64;
    ushortT* dst = Wit + ((size_t)hs * D_ + o) * D_ + dbase;
#pragma unroll
    for (int c = 0; c < 8; ++c) {
      uint4v pk;
#pragma unroll
      for (int q = 0; q < 4; ++q) {
        ushortT lo = tile[(dbase + c * 8 + q * 2) * 136 + o];
        ushortT hi = tile[(dbase + c * 8 + q * 2 + 1) * 136 + o];
        pk[q] = (uint32)lo | ((uint32)hi << 16);
      }
      *(uint4v*)(dst + c * 8) = pk;
    }
  } else {
    int hs = bx - 128; int h = hs >> 4, s = hs & 15;
    const float* src = Wj + (size_t)hs * 256 * D_;
    for (int half = 0; half < 2; ++half) {
      if (half) __syncthreads();
#pragma unroll 4
      for (int i = 0; i < 64; ++i) {
        int e = t + 256 * i;
        int dd = e >> 7, o = e & 127;
        tile[dd * 136 + o] = f2bf(src[half * 16384 + e]);
      }
      __syncthreads();
      int o = t >> 1, db = (t & 1) * 64;
      int part = half * 2 + (t & 1);
      ushortT* dst = Wjt_sw + ((size_t)(h * 16 + s) * 4 + part) * 8192;
#pragma unroll
      for (int c = 0; c < 8; ++c) {
        uint4v pk;
#pragma unroll
        for (int q = 0; q < 4; ++q) {
          ushortT lo = tile[(db + c * 8 + q * 2) * 136 + o];
          ushortT hi = tile[(db + c * 8 + q * 2 + 1) * 136 + o];
          pk[q] = (uint32)lo | ((uint32)hi << 16);
        }
        *(uint4v*)(dst + (o * 8 + (c ^ (o & 7))) * 8) = pk;
      }
    }
  }
}

// ---------------------------------------------------------------------------
// K1: se[b,h,s,:] = enc[b,s,:] @ Wi[h,s] for 4 h per block; per-(s,b,h)
// sum/sumsq partials. grid (16 bt, 16 s, 2 hp)
// ---------------------------------------------------------------------------
__global__ __launch_bounds__(256) void k_gemm1(const ushortT* __restrict__ enc,
                                               const ushortT* __restrict__ Wit,
                                               ushortT* __restrict__ se,
                                               float* __restrict__ ssum,
                                               float* __restrict__ ssq) {
  int bt = blockIdx.x, s = blockIdx.y, hp = blockIdx.z;
  int h0 = hp * 4;
  __shared__ ushortT As[128 * 128];
  __shared__ ushortT Bs[128 * 128];
  int tid = threadIdx.x;
  int c16 = tid & 15, prow = tid >> 4;
  int wave = tid >> 6, lane = tid & 63;
  int l15 = lane & 15, lg = lane >> 4;

  ushort8 rb[8];
#pragma unroll
  for (int i = 0; i < 8; ++i) {
    int row = prow + 16 * i;
    int sw = ((c16 ^ (row & 7)) * 8);
    ushort8 va = *(const ushort8*)(enc + (size_t)(bt * 128 + row) * (S_ * D_) + s * D_ + c16 * 8);
    *(ushort8*)(As + row * 128 + sw) = va;
    rb[i] = *(const ushort8*)(Wit + ((size_t)((h0 * S_ + s) * D_) + row) * D_ + c16 * 8);
  }
  __syncthreads();
  short8 afr[4][2];
#pragma unroll
  for (int kk = 0; kk < 4; ++kk)
#pragma unroll
    for (int i = 0; i < 2; ++i) {
      int row = wave * 32 + i * 16 + l15;
      int cc = kk * 4 + lg;
      afr[kk][i] = *(const short8*)(As + row * 128 + ((cc ^ (row & 7)) * 8));
    }

  for (int hh = 0; hh < 4; ++hh) {
    int h = h0 + hh;
    if (hh) __syncthreads();
#pragma unroll
    for (int i = 0; i < 8; ++i) {
      int row = prow + 16 * i;
      *(ushort8*)(Bs + row * 128 + ((c16 ^ (row & 7)) * 8)) = rb[i];
    }
    if (hh < 3) {
#pragma unroll
      for (int i = 0; i < 8; ++i) {
        int row = prow + 16 * i;
        rb[i] = *(const ushort8*)(Wit + ((size_t)(((h + 1) * S_ + s) * D_) + row) * D_ + c16 * 8);
      }
    }
    __syncthreads();
    f32x4 acc[2][8];
#pragma unroll
    for (int i = 0; i < 2; ++i)
#pragma unroll
      for (int j = 0; j < 8; ++j) acc[i][j] = (f32x4)(0.f);
#pragma unroll
    for (int kk = 0; kk < 4; ++kk) {
      int cc = kk * 4 + lg;
      short8 b[8];
#pragma unroll
      for (int j = 0; j < 8; ++j) {
        int row = j * 16 + l15;
        b[j] = *(const short8*)(Bs + row * 128 + ((cc ^ (row & 7)) * 8));
      }
#pragma unroll
      for (int i = 0; i < 2; ++i)
#pragma unroll
        for (int j = 0; j < 8; ++j)
          acc[i][j] = __builtin_amdgcn_mfma_f32_16x16x32_bf16(afr[kk][i], b[j], acc[i][j], 0, 0, 0);
    }
#pragma unroll
    for (int i = 0; i < 2; ++i)
#pragma unroll
      for (int rr = 0; rr < 4; ++rr) {
        int rloc = wave * 32 + i * 16 + lg * 4 + rr;
        int b_g = bt * 128 + rloc;
        float rs = 0.f, rq = 0.f;
#pragma unroll
        for (int j = 0; j < 8; ++j) {
          float val = acc[i][j][rr];
          rs += val; rq += val * val;
        }
#pragma unroll
        for (int m = 1; m <= 8; m <<= 1) {
          rs += __shfl_xor(rs, m);
          rq += __shfl_xor(rq, m);
        }
        if (l15 == 0) {
          ssum[((size_t)s * N_ + b_g) * H_ + h] = rs;
          ssq[((size_t)s * N_ + b_g) * H_ + h] = rq;
        }
      }
    __syncthreads();
#pragma unroll
    for (int i = 0; i < 2; ++i)
#pragma unroll
      for (int rr = 0; rr < 4; ++rr) {
        int row = wave * 32 + i * 16 + lg * 4 + rr;
        int sw = (row & 7) << 3;
#pragma unroll
        for (int j = 0; j < 8; ++j) {
          int o = j * 16 + l15;
          Bs[row * 128 + (o ^ sw)] = f2bf(acc[i][j][rr]);
        }
      }
    __syncthreads();
#pragma unroll
    for (int p = 0; p < 2; ++p) {
      int row = p * 64 + (tid >> 2);
      int sw = (row & 7) << 3;
      int b_g = bt * 128 + row;
      ushortT* dst = se + (((size_t)b_g * H_ + h) * S_ + s) * D_;
#pragma unroll
      for (int q = 0; q < 4; ++q) {
        int o0 = (q * 4 + (tid & 3)) * 8;
        *(uint4v*)(dst + o0) = *(const uint4v*)(Bs + row * 128 + (o0 ^ sw));
      }
    }
  }
}

// ---------------------------------------------------------------------------
// K2: LN1 stats finalize -> (rstd, -mu*rstd) per (b,h)
// ---------------------------------------------------------------------------
__global__ __launch_bounds__(256) void k_finalize(const float* __restrict__ ssum,
                                                  const float* __restrict__ ssq,
                                                  float* __restrict__ mr) {
  int t = blockIdx.x * 256 + threadIdx.x;  // N*H = 16384
  float s1 = 0.f, s2 = 0.f;
#pragma unroll
  for (int s = 0; s < S_; ++s) {
    s1 += ssum[(size_t)s * (N_ * H_) + t];
    s2 += ssq[(size_t)s * (N_ * H_) + t];
  }
  float mu = s1 * (1.f / 2048.f);
  float var = s2 * (1.f / 2048.f) - mu * mu;
  float rstd = rsqrtf(var + EPS_);
  mr[t * 2] = rstd;
  mr[t * 2 + 1] = -mu * rstd;
}

// ---------------------------------------------------------------------------
// K3: out_part[sh] = sum over scount s of [diff | act(LN1(se))] @ Wj[h,s]
// Double-buffered, ONE __syncthreads per BK=64 chunk. diff & Wjt staged via
// global_load_lds from pre-swizzled layouts; se reg-staged with fused
// LN1+PReLU (fma-form + v_cvt_pk_bf16_f32).
// Phases per s: p0=diff-lo, p1=diff-hi, p2=se-lo, p3=se-hi.
// ---------------------------------------------------------------------------
#define GLDS_TILE(DST, SRC) do {                                              \
    const ushortT* sp_ = (SRC) + wave * 512 + lane * 8;                       \
    ushortT* dp_ = (DST) + wave * 512;                                        \
    _Pragma("unroll")                                                         \
    for (int i_ = 0; i_ < 4; ++i_)                                            \
      __builtin_amdgcn_global_load_lds(                                       \
          (const __attribute__((address_space(1))) void*)(sp_ + i_ * 2048),   \
          (__attribute__((address_space(3))) void*)(dp_ + i_ * 2048),         \
          16, 0, 0);                                                          \
  } while (0)

__global__ __launch_bounds__(256, 2) void k_gemm2(const ushortT* __restrict__ diff_sw,
                                                  const ushortT* __restrict__ se,
                                                  const ushortT* __restrict__ Wjt_sw,
                                                  const float* __restrict__ mr,
                                                  const float* __restrict__ ln1w,
                                                  const float* __restrict__ ln1b,
                                                  const float* __restrict__ pa1,
                                                  float* __restrict__ outp,
                                                  int scount) {
  int bt = blockIdx.x, sh = blockIdx.y, h = blockIdx.z;
  int s0 = sh * scount;
  __shared__ ushortT As[2][128 * 64];
  __shared__ ushortT Bs[2][128 * 64];
  int tid = threadIdx.x;
  int wave = tid >> 6, lane = tid & 63;
  int c8 = tid & 7, trow = tid >> 3;
  int swst = ((c8 ^ (trow & 7)) * 8);
  int l15 = lane & 15, lg = lane >> 4;
  int wm = wave >> 1, wn = wave & 1;
  float a1 = pa1[0];

  float rs_r[4], nm_r[4];
  uint32 aoff_s[4];
#pragma unroll
  for (int i = 0; i < 4; ++i) {
    int row = i * 32 + trow;
    int b_g = bt * 128 + row;
    rs_r[i] = mr[((size_t)b_g * H_ + h) * 2];
    nm_r[i] = mr[((size_t)b_g * H_ + h) * 2 + 1];
    aoff_s[i] = ((uint32)b_g * H_ + h) * (S_ * D_) + c8 * 8;
  }
  ushort8 raL[4], raH[4];
  f32x4 acc[4][4];
#pragma unroll
  for (int i = 0; i < 4; ++i)
#pragma unroll
    for (int j = 0; j < 4; ++j) acc[i][j] = (f32x4)(0.f);

#define COMPUTE(XBUF) do {                                                    \
    _Pragma("unroll")                                                         \
    for (int kk = 0; kk < 2; ++kk) {                                          \
      int cc = kk * 4 + lg;                                                   \
      short8 a[4], b[4];                                                      \
      _Pragma("unroll")                                                       \
      for (int i = 0; i < 4; ++i) {                                           \
        int row = wm * 64 + i * 16 + l15;                                     \
        a[i] = *(const short8*)(As[XBUF] + row * 64 + ((cc ^ (row & 7)) * 8));\
      }                                                                       \
      _Pragma("unroll")                                                       \
      for (int j = 0; j < 4; ++j) {                                           \
        int row = wn * 64 + j * 16 + l15;                                     \
        b[j] = *(const short8*)(Bs[XBUF] + row * 64 + ((cc ^ (row & 7)) * 8));\
      }                                                                       \
      _Pragma("unroll")                                                       \
      for (int i = 0; i < 4; ++i)                                             \
        _Pragma("unroll")                                                     \
        for (int j = 0; j < 4; ++j)                                           \
          acc[i][j] = __builtin_amdgcn_mfma_f32_16x16x32_bf16(a[i], b[j],     \
                                                              acc[i][j], 0, 0, 0); \
    } } while (0)

#define TRANSFORM_WRITE(RA, NXBUF, SS, HALF) do {                             \
    float8 w8 = *(const float8*)(ln1w + (SS) * D_ + (HALF) * 64 + c8 * 8);    \
    float8 b8 = *(const float8*)(ln1b + (SS) * D_ + (HALF) * 64 + c8 * 8);    \
    _Pragma("unroll")                                                         \
    for (int i = 0; i < 4; ++i) {                                             \
      int row = i * 32 + trow;                                                \
      float y[8];                                                             \
      _Pragma("unroll")                                                       \
      for (int e = 0; e < 8; ++e) {                                           \
        float f = bf2f((ushortT)RA[i][e]);                                    \
        float tt = fmaf(f, rs_r[i], nm_r[i]);                                 \
        float vv = fmaf(tt, w8[e], b8[e]);                                    \
        y[e] = fmaf(a1, fminf(vv, 0.f), fmaxf(vv, 0.f));                      \
      }                                                                       \
      uint4v pk;                                                              \
      _Pragma("unroll")                                                       \
      for (int q = 0; q < 4; ++q) {                                           \
        uint32 rpk;                                                           \
        asm("v_cvt_pk_bf16_f32 %0, %1, %2" : "=v"(rpk)                        \
            : "v"(y[2 * q]), "v"(y[2 * q + 1]));                              \
        pk[q] = rpk;                                                          \
      }                                                                       \
      *(uint4v*)(As[NXBUF] + row * 64 + swst) = pk;                           \
    } } while (0)

  // prologue: chunk 0 (s0, diff-lo) into buf0
  GLDS_TILE(As[0], diff_sw + ((size_t)(bt * 16 + s0) * 2 + 0) * 8192);
  GLDS_TILE(Bs[0], Wjt_sw + ((size_t)(h * 16 + s0) * 4 + 0) * 8192);
  __syncthreads();

  for (int si = 0; si < scount; ++si) {
    int s = s0 + si;
    int sn = (s + 1 < S_) ? s + 1 : 0;  // wrap: staged junk never computed
    // ---- phase 0: compute (s,p0) from buf0; stage (s,p1)->buf1; load se-lo
#pragma unroll
    for (int i = 0; i < 4; ++i)
      raL[i] = *(const ushort8*)(se + aoff_s[i] + s * D_);
    GLDS_TILE(As[1], diff_sw + ((size_t)(bt * 16 + s) * 2 + 1) * 8192);
    GLDS_TILE(Bs[1], Wjt_sw + ((size_t)(h * 16 + s) * 4 + 1) * 8192);
    COMPUTE(0);
    __syncthreads();
    // ---- phase 1: compute (s,p1) from buf1; stage se-lo->buf0; load se-hi
#pragma unroll
    for (int i = 0; i < 4; ++i)
      raH[i] = *(const ushort8*)(se + aoff_s[i] + s * D_ + 64);
    TRANSFORM_WRITE(raL, 0, s, 0);
    GLDS_TILE(Bs[0], Wjt_sw + ((size_t)(h * 16 + s) * 4 + 2) * 8192);
    COMPUTE(1);
    __syncthreads();
    // ---- phase 2: compute (s,p2) from buf0; stage se-hi->buf1
    TRANSFORM_WRITE(raH, 1, s, 1);
    GLDS_TILE(Bs[1], Wjt_sw + ((size_t)(h * 16 + s) * 4 + 3) * 8192);
    COMPUTE(0);
    __syncthreads();
    // ---- phase 3: compute (s,p3) from buf1; stage (s+1,p0)->buf0
    GLDS_TILE(As[0], diff_sw + ((size_t)(bt * 16 + sn) * 2 + 0) * 8192);
    GLDS_TILE(Bs[0], Wjt_sw + ((size_t)(h * 16 + sn) * 4 + 0) * 8192);
    COMPUTE(1);
    __syncthreads();
  }

#pragma unroll
  for (int i = 0; i < 4; ++i)
#pragma unroll
    for (int j = 0; j < 4; ++j)
#pragma unroll
      for (int rr = 0; rr < 4; ++rr) {
        int b_g = bt * 128 + wm * 64 + i * 16 + lg * 4 + rr;
        int o = wn * 64 + j * 16 + l15;
        outp[(((size_t)sh * N_ + b_g) * H_ + h) * D_ + o] = acc[i][j][rr];
      }
}

// ---------------------------------------------------------------------------
// K4: combine nsplit K-partials, LN2 over (H,D)=1024 per b, PReLU, f32 out
// ---------------------------------------------------------------------------
__global__ __launch_bounds__(256) void k_ln2(const float* __restrict__ outp,
                                             const float* __restrict__ ln2w,
                                             const float* __restrict__ ln2b,
                                             const float* __restrict__ pa2,
                                             float* __restrict__ out,
                                             int nsplit) {
  int b = blockIdx.x, t = threadIdx.x;
  __shared__ float red[8];
  __shared__ float stats[2];
  f32x4 v = (f32x4)(0.f);
  for (int p = 0; p < nsplit; ++p)
    v += *((const f32x4*)(outp + (size_t)p * (N_ * 1024) + (size_t)b * 1024) + t);
  float s1 = v[0] + v[1] + v[2] + v[3];
  float s2 = v[0] * v[0] + v[1] * v[1] + v[2] * v[2] + v[3] * v[3];
#pragma unroll
  for (int m = 1; m <= 32; m <<= 1) {
    s1 += __shfl_xor(s1, m);
    s2 += __shfl_xor(s2, m);
  }
  int wave = t >> 6, lane = t & 63;
  if (lane == 0) { red[wave] = s1; red[4 + wave] = s2; }
  __syncthreads();
  if (t == 0) {
    float S = red[0] + red[1] + red[2] + red[3];
    float Q = red[4] + red[5] + red[6] + red[7];
    float mu = S * (1.f / 1024.f);
    float var = Q * (1.f / 1024.f) - mu * mu;
    stats[0] = mu; stats[1] = rsqrtf(var + EPS_);
  }
  __syncthreads();
  float mu = stats[0], rstd = stats[1];
  float a2 = pa2[0];
  f32x4 wv = *((const f32x4*)ln2w + t);
  f32x4 bv = *((const f32x4*)ln2b + t);
  f32x4 r;
#pragma unroll
  for (int e = 0; e < 4; ++e) {
    float y = (v[e] - mu) * rstd * wv[e] + bv[e];
    r[e] = (y >= 0.f) ? y : a2 * y;
  }
  *((f32x4*)(out + (size_t)b * 1024) + t) = r;
}

// ---------------------------------------------------------------------------
extern "C" void kernel_launch(void* const* d_in, const int* in_sizes, int n_in,
                              void* d_out, int out_size, void* d_ws, size_t ws_size,
                              hipStream_t stream) {
  const float* x    = (const float*)d_in[0];
  const float* Wi   = (const float*)d_in[1];
  const float* Wj   = (const float*)d_in[2];
  const float* ln1w = (const float*)d_in[3];
  const float* ln1b = (const float*)d_in[4];
  const float* pa1  = (const float*)d_in[5];
  const float* ln2w = (const float*)d_in[6];
  const float* ln2b = (const float*)d_in[7];
  const float* pa2  = (const float*)d_in[8];
  char* ws = (char*)d_ws;
  // ws layout with liveness overlay:
  //   [0,64M)          se      (gemm1 -> gemm2)
  //   [64M,72M)        diff_sw (prep -> gemm2)
  //   [72M,80M)        Wjt_sw  (castW -> gemm2)
  //   [80M,80M+ns*8M)  outp    (gemm2 -> ln2), OVERLAYS (dead before gemm2):
  //       [80M,88M)     enc   (prep -> gemm1)
  //       [88M,92M)     Wit   (castW -> gemm1)
  //       [92M,93M)     ssum  (gemm1 -> finalize)
  //       [93M,94M)     ssq
  //   [80M+ns*8M, +128K) mr   (finalize -> gemm2; must NOT overlay outp)
  ushortT* se      = (ushortT*)(ws + 0);
  ushortT* diff_sw = (ushortT*)(ws + 67108864);
  ushortT* Wjt_sw  = (ushortT*)(ws + 75497472);
  float*   outp    = (float*)(ws + 83886080);
  ushortT* enc     = (ushortT*)(ws + 83886080);
  ushortT* Wit     = (ushortT*)(ws + 92274688);
  float*   ssum    = (float*)(ws + 96468992);
  float*   ssq     = (float*)(ws + 97517568);
  float*   out     = (float*)d_out;

  int nsplit = (ws_size >= 117571584ull) ? 4 : 2;
  int scount = S_ / nsplit;
  float* mr = (float*)(ws + 83886080 + (size_t)nsplit * 8388608);

  hipLaunchKernelGGL(k_prep, dim3(1024), dim3(256), 0, stream, x, enc, diff_sw);
  hipLaunchKernelGGL(k_castW, dim3(256), dim3(256), 0, stream, Wi, Wj, Wit, Wjt_sw);
  hipLaunchKernelGGL(k_gemm1, dim3(16, 16, 2), dim3(256), 0, stream, enc, Wit, se, ssum, ssq);
  hipLaunchKernelGGL(k_finalize, dim3(64), dim3(256), 0, stream, ssum, ssq, mr);
  hipLaunchKernelGGL(k_gemm2, dim3(16, nsplit, 8), dim3(256), 0, stream, diff_sw, se, Wjt_sw, mr,
                     ln1w, ln1b, pa1, outp, scount);
  hipLaunchKernelGGL(k_ln2, dim3(2048), dim3(256), 0, stream, outp, ln2w, ln2b, pa2, out, nsplit);
}

// Round 5
// 188.401 us; speedup vs baseline: 1.3849x; 1.0408x over previous
//
#include <hip/hip_runtime.h>

#define N_ 2048
#define S_ 16
#define D_ 128
#define H_ 8
#define EPS_ 1e-5f

typedef unsigned short ushortT;
typedef unsigned int uint32;
typedef __attribute__((ext_vector_type(8))) short short8;
typedef __attribute__((ext_vector_type(8))) unsigned short ushort8;
typedef __attribute__((ext_vector_type(4))) float f32x4;
typedef __attribute__((ext_vector_type(4))) unsigned int uint4v;
typedef __attribute__((ext_vector_type(8))) float float8;

__device__ __forceinline__ ushortT f2bf(float f) {
  union { float f; uint32 u; } c; c.f = f;
  uint32 u = c.u;
  u = (u + 0x7FFFu + ((u >> 16) & 1u)) >> 16;  // RNE
  return (ushortT)u;
}
__device__ __forceinline__ float bf2f(ushortT b) {
  union { uint32 u; float f; } c; c.u = ((uint32)b) << 16;
  return c.f;
}

// ---------------------------------------------------------------------------
// K0: per-(n,d) column: stable-descending ranks over S=16.
// enc -> enc_sw: MFMA-A-fragment order, [bt][s][wave][kk][i][lane][8e]
//   (gemm1 A-frag loads become wave-uniform-base + lane*16B, fully coalesced)
// diff -> diff_sw: glds-linear swizzled tiles for gemm2 (unchanged layout).
// ---------------------------------------------------------------------------
__global__ __launch_bounds__(256) void k_prep(const float* __restrict__ x,
                                              ushortT* __restrict__ enc_sw,
                                              ushortT* __restrict__ diff_sw) {
  int g = blockIdx.x * 256 + threadIdx.x;  // N*D = 262144 threads
  int n = g >> 7, d = g & 127;
  const float* xp = x + (size_t)n * (S_ * D_) + d;
  float v[S_];
#pragma unroll
  for (int s = 0; s < S_; ++s) v[s] = xp[s * D_];
  int r[S_];
#pragma unroll
  for (int i = 0; i < S_; ++i) {
    int ri = 0;
#pragma unroll
    for (int j = 0; j < S_; ++j)
      ri += ((v[j] > v[i]) || (v[j] == v[i] && j < i)) ? 1 : 0;
    r[i] = ri;
  }
  float xs[S_ + 1];
#pragma unroll
  for (int s = 0; s < S_; ++s) {
    float acc = 0.f;
#pragma unroll
    for (int i = 0; i < S_; ++i) acc += (r[i] == s) ? v[i] : 0.f;
    xs[s] = acc;
  }
  xs[S_] = 0.f;
  // enc_sw addressing (fragment order)
  int btq = n >> 7, row = n & 127;
  int wv = row >> 5, ii = (row >> 4) & 1, l = row & 15;
  int kkm = d >> 5, lgm = (d >> 3) & 3, em = d & 7;
  int off_nd = (((kkm * 2 + ii) * 64) + (lgm * 16 + l)) * 8 + em;
  // diff_sw addressing (glds-linear swizzled)
  int pp = d >> 6, c8p = (d >> 3) & 7, ee = d & 7;
  int q = row * 8 + (c8p ^ (row & 7));
#pragma unroll
  for (int s = 0; s < S_; ++s) {
    uint32 mm = 0;
#pragma unroll
    for (int i = 0; i < S_; ++i) mm |= (r[i] <= s) ? (1u << i) : 0u;
    enc_sw[(size_t)((btq * 16 + s) * 4 + wv) * 4096 + off_nd] =
        f2bf((float)mm * (1.f / 65536.f));
    size_t idx = ((((size_t)(btq * 16 + s) * 2 + pp) * 1024) + q) * 8 + ee;
    diff_sw[idx] = f2bf(xs[s] - xs[s + 1]);
  }
}

// ---------------------------------------------------------------------------
// K0b: merged weight casts, all stores lane-linear (coalesced); the swizzle
// is applied by inverse-permutation on the LDS read side.
//  blocks [0,128):   Wi[h][s][d][o] -> Wit_sw[hs][q*8], q = o*16 + (cc^(o&7))
//  blocks [128,256): Wj[h][s][dd][o] -> Wjt_sw[hs][part][q*8], q = o*8+(c8^(o&7))
// ---------------------------------------------------------------------------
__global__ __launch_bounds__(256) void k_castW(const float* __restrict__ Wi,
                                               const float* __restrict__ Wj,
                                               ushortT* __restrict__ Wit_sw,
                                               ushortT* __restrict__ Wjt_sw) {
  __shared__ ushortT tile[128 * 136];
  int bx = blockIdx.x;
  int t = threadIdx.x;
  if (bx < 128) {
    int hs = bx;
    const float* src = Wi + (size_t)hs * D_ * D_;
#pragma unroll 4
    for (int i = 0; i < 64; ++i) {
      int e = t + 256 * i;
      int dd = e >> 7, o = e & 127;
      tile[dd * 136 + o] = f2bf(src[e]);
    }
    __syncthreads();
    ushortT* dst = Wit_sw + (size_t)hs * 16384;
#pragma unroll
    for (int r8 = 0; r8 < 8; ++r8) {
      int qc = r8 * 256 + t;              // linear chunk 0..2047
      int o = qc >> 4;
      int cc = (qc & 15) ^ (o & 7);       // recovered K-chunk
      uint4v pk;
#pragma unroll
      for (int w = 0; w < 4; ++w) {
        int d0 = cc * 8 + w * 2;
        ushortT lo = tile[d0 * 136 + o];
        ushortT hi = tile[(d0 + 1) * 136 + o];
        pk[w] = (uint32)lo | ((uint32)hi << 16);
      }
      *(uint4v*)(dst + qc * 8) = pk;      // consecutive lanes -> consecutive 16B
    }
  } else {
    int hs = bx - 128;
    const float* src = Wj + (size_t)hs * 256 * D_;
    for (int half = 0; half < 2; ++half) {
      if (half) __syncthreads();
#pragma unroll 4
      for (int i = 0; i < 64; ++i) {
        int e = t + 256 * i;
        int dd = e >> 7, o = e & 127;
        tile[dd * 136 + o] = f2bf(src[half * 16384 + e]);
      }
      __syncthreads();
      ushortT* dstb = Wjt_sw + ((size_t)hs * 4 + half * 2) * 8192;
#pragma unroll
      for (int r8 = 0; r8 < 8; ++r8) {
        int cg = r8 * 256 + t;            // 0..2047
        int pl = cg >> 10;                // part within half
        int qc = cg & 1023;
        int o = qc >> 3;
        int c8 = (qc & 7) ^ (o & 7);
        int dl = pl * 64 + c8 * 8;        // dd_local base
        uint4v pk;
#pragma unroll
        for (int w = 0; w < 4; ++w) {
          ushortT lo = tile[(dl + w * 2) * 136 + o];
          ushortT hi = tile[(dl + w * 2 + 1) * 136 + o];
          pk[w] = (uint32)lo | ((uint32)hi << 16);
        }
        *(uint4v*)(dstb + (size_t)pl * 8192 + qc * 8) = pk;
      }
    }
  }
}

// ---------------------------------------------------------------------------
// K1: se[b,h,s,:] = enc[b,s,:] @ Wi[h,s]; per-(s,b,h) sum/sumsq partials.
// 1 h per block, grid (16,16,8) = 2048 blocks. LDS = 33KB (B-tile via glds,
// A-frags direct from enc_sw, C^T reuses B buffer at stride 132).
// ---------------------------------------------------------------------------
__global__ __launch_bounds__(256, 3) void k_gemm1(const ushortT* __restrict__ enc_sw,
                                                  const ushortT* __restrict__ Wit_sw,
                                                  ushortT* __restrict__ se,
                                                  float* __restrict__ ssum,
                                                  float* __restrict__ ssq) {
  int bt = blockIdx.x, s = blockIdx.y, h = blockIdx.z;
  __shared__ ushortT Bs[128 * 132];  // 33 KB
  int tid = threadIdx.x;
  int wave = tid >> 6, lane = tid & 63;
  int l15 = lane & 15, lg = lane >> 4;

  // stage B tile (32KB) via global_load_lds from pre-swizzled Wit_sw
  const ushortT* bsrc = Wit_sw + (size_t)(h * 16 + s) * 16384;
#pragma unroll
  for (int r8 = 0; r8 < 8; ++r8)
    __builtin_amdgcn_global_load_lds(
        (const __attribute__((address_space(1))) void*)(bsrc + (r8 * 256 + tid) * 8),
        (__attribute__((address_space(3))) void*)(Bs + (r8 * 256 + wave * 64) * 8),
        16, 0, 0);

  // A fragments direct from enc_sw (coalesced 16B/lane)
  short8 afr[4][2];
  const ushortT* abase = enc_sw + ((size_t)(bt * 16 + s) * 4 + wave) * 4096;
#pragma unroll
  for (int kk = 0; kk < 4; ++kk)
#pragma unroll
    for (int i = 0; i < 2; ++i)
      afr[kk][i] = *(const short8*)(abase + ((kk * 2 + i) * 64 + lane) * 8);

  __syncthreads();  // drains glds (vmcnt 0 before barrier)

  f32x4 acc[2][8];
#pragma unroll
  for (int i = 0; i < 2; ++i)
#pragma unroll
    for (int j = 0; j < 8; ++j) acc[i][j] = (f32x4)(0.f);
#pragma unroll
  for (int kk = 0; kk < 4; ++kk) {
    int cc = kk * 4 + lg;
    short8 b[8];
#pragma unroll
    for (int j = 0; j < 8; ++j) {
      int row = j * 16 + l15;
      b[j] = *(const short8*)(Bs + (row * 16 + (cc ^ (row & 7))) * 8);
    }
#pragma unroll
    for (int i = 0; i < 2; ++i)
#pragma unroll
      for (int j = 0; j < 8; ++j)
        acc[i][j] = __builtin_amdgcn_mfma_f32_16x16x32_bf16(afr[kk][i], b[j], acc[i][j], 0, 0, 0);
  }
  // stats partials
#pragma unroll
  for (int i = 0; i < 2; ++i)
#pragma unroll
    for (int rr = 0; rr < 4; ++rr) {
      int rloc = wave * 32 + i * 16 + lg * 4 + rr;
      int b_g = bt * 128 + rloc;
      float rs = 0.f, rq = 0.f;
#pragma unroll
      for (int j = 0; j < 8; ++j) {
        float val = acc[i][j][rr];
        rs += val; rq += val * val;
      }
#pragma unroll
      for (int m = 1; m <= 8; m <<= 1) {
        rs += __shfl_xor(rs, m);
        rq += __shfl_xor(rq, m);
      }
      if (l15 == 0) {
        ssum[((size_t)s * N_ + b_g) * H_ + h] = rs;
        ssq[((size_t)s * N_ + b_g) * H_ + h] = rq;
      }
    }
  __syncthreads();  // all MFMA reads of Bs done
  // C^T into Bs at stride 132 (lg-groups spread over banks)
#pragma unroll
  for (int i = 0; i < 2; ++i)
#pragma unroll
    for (int rr = 0; rr < 4; ++rr) {
      int row = wave * 32 + i * 16 + lg * 4 + rr;
      int sw = (row & 7) << 3;
#pragma unroll
      for (int j = 0; j < 8; ++j) {
        int o = j * 16 + l15;
        Bs[row * 132 + (o ^ sw)] = f2bf(acc[i][j][rr]);
      }
    }
  __syncthreads();
#pragma unroll
  for (int p = 0; p < 2; ++p) {
    int row = p * 64 + (tid >> 2);
    int sw = (row & 7) << 3;
    int b_g = bt * 128 + row;
    ushortT* dst = se + (((size_t)b_g * H_ + h) * S_ + s) * D_;
#pragma unroll
    for (int qq = 0; qq < 4; ++qq) {
      int o0 = (qq * 4 + (tid & 3)) * 8;
      *(uint4v*)(dst + o0) = *(const uint4v*)(Bs + row * 132 + (o0 ^ sw));
    }
  }
}

// ---------------------------------------------------------------------------
// K2: LN1 stats finalize -> (rstd, -mu*rstd) per (b,h)
// ---------------------------------------------------------------------------
__global__ __launch_bounds__(256) void k_finalize(const float* __restrict__ ssum,
                                                  const float* __restrict__ ssq,
                                                  float* __restrict__ mr) {
  int t = blockIdx.x * 256 + threadIdx.x;  // N*H = 16384
  float s1 = 0.f, s2 = 0.f;
#pragma unroll
  for (int s = 0; s < S_; ++s) {
    s1 += ssum[(size_t)s * (N_ * H_) + t];
    s2 += ssq[(size_t)s * (N_ * H_) + t];
  }
  float mu = s1 * (1.f / 2048.f);
  float var = s2 * (1.f / 2048.f) - mu * mu;
  float rstd = rsqrtf(var + EPS_);
  mr[t * 2] = rstd;
  mr[t * 2 + 1] = -mu * rstd;
}

// ---------------------------------------------------------------------------
// K3: out_part[sh] = sum over scount s of [diff | act(LN1(se))] @ Wj[h,s]
// Double-buffered, ONE __syncthreads per BK=64 chunk. (unchanged from r4)
// ---------------------------------------------------------------------------
#define GLDS_TILE(DST, SRC) do {                                              \
    const ushortT* sp_ = (SRC) + wave * 512 + lane * 8;                       \
    ushortT* dp_ = (DST) + wave * 512;                                        \
    _Pragma("unroll")                                                         \
    for (int i_ = 0; i_ < 4; ++i_)                                            \
      __builtin_amdgcn_global_load_lds(                                       \
          (const __attribute__((address_space(1))) void*)(sp_ + i_ * 2048),   \
          (__attribute__((address_space(3))) void*)(dp_ + i_ * 2048),         \
          16, 0, 0);                                                          \
  } while (0)

__global__ __launch_bounds__(256, 2) void k_gemm2(const ushortT* __restrict__ diff_sw,
                                                  const ushortT* __restrict__ se,
                                                  const ushortT* __restrict__ Wjt_sw,
                                                  const float* __restrict__ mr,
                                                  const float* __restrict__ ln1w,
                                                  const float* __restrict__ ln1b,
                                                  const float* __restrict__ pa1,
                                                  float* __restrict__ outp,
                                                  int scount) {
  int bt = blockIdx.x, sh = blockIdx.y, h = blockIdx.z;
  int s0 = sh * scount;
  __shared__ ushortT As[2][128 * 64];
  __shared__ ushortT Bs[2][128 * 64];
  int tid = threadIdx.x;
  int wave = tid >> 6, lane = tid & 63;
  int c8 = tid & 7, trow = tid >> 3;
  int swst = ((c8 ^ (trow & 7)) * 8);
  int l15 = lane & 15, lg = lane >> 4;
  int wm = wave >> 1, wn = wave & 1;
  float a1 = pa1[0];

  float rs_r[4], nm_r[4];
  uint32 aoff_s[4];
#pragma unroll
  for (int i = 0; i < 4; ++i) {
    int row = i * 32 + trow;
    int b_g = bt * 128 + row;
    rs_r[i] = mr[((size_t)b_g * H_ + h) * 2];
    nm_r[i] = mr[((size_t)b_g * H_ + h) * 2 + 1];
    aoff_s[i] = ((uint32)b_g * H_ + h) * (S_ * D_) + c8 * 8;
  }
  ushort8 raL[4], raH[4];
  f32x4 acc[4][4];
#pragma unroll
  for (int i = 0; i < 4; ++i)
#pragma unroll
    for (int j = 0; j < 4; ++j) acc[i][j] = (f32x4)(0.f);

#define COMPUTE(XBUF) do {                                                    \
    _Pragma("unroll")                                                         \
    for (int kk = 0; kk < 2; ++kk) {                                          \
      int cc = kk * 4 + lg;                                                   \
      short8 a[4], b[4];                                                      \
      _Pragma("unroll")                                                       \
      for (int i = 0; i < 4; ++i) {                                           \
        int row = wm * 64 + i * 16 + l15;                                     \
        a[i] = *(const short8*)(As[XBUF] + row * 64 + ((cc ^ (row & 7)) * 8));\
      }                                                                       \
      _Pragma("unroll")                                                       \
      for (int j = 0; j < 4; ++j) {                                           \
        int row = wn * 64 + j * 16 + l15;                                     \
        b[j] = *(const short8*)(Bs[XBUF] + row * 64 + ((cc ^ (row & 7)) * 8));\
      }                                                                       \
      _Pragma("unroll")                                                       \
      for (int i = 0; i < 4; ++i)                                             \
        _Pragma("unroll")                                                     \
        for (int j = 0; j < 4; ++j)                                           \
          acc[i][j] = __builtin_amdgcn_mfma_f32_16x16x32_bf16(a[i], b[j],     \
                                                              acc[i][j], 0, 0, 0); \
    } } while (0)

#define TRANSFORM_WRITE(RA, NXBUF, SS, HALF) do {                             \
    float8 w8 = *(const float8*)(ln1w + (SS) * D_ + (HALF) * 64 + c8 * 8);    \
    float8 b8 = *(const float8*)(ln1b + (SS) * D_ + (HALF) * 64 + c8 * 8);    \
    _Pragma("unroll")                                                         \
    for (int i = 0; i < 4; ++i) {                                             \
      int row = i * 32 + trow;                                                \
      float y[8];                                                             \
      _Pragma("unroll")                                                       \
      for (int e = 0; e < 8; ++e) {                                           \
        float f = bf2f((ushortT)RA[i][e]);                                    \
        float tt = fmaf(f, rs_r[i], nm_r[i]);                                 \
        float vv = fmaf(tt, w8[e], b8[e]);                                    \
        y[e] = fmaf(a1, fminf(vv, 0.f), fmaxf(vv, 0.f));                      \
      }                                                                       \
      uint4v pk;                                                              \
      _Pragma("unroll")                                                       \
      for (int q = 0; q < 4; ++q) {                                           \
        uint32 rpk;                                                           \
        asm("v_cvt_pk_bf16_f32 %0, %1, %2" : "=v"(rpk)                        \
            : "v"(y[2 * q]), "v"(y[2 * q + 1]));                              \
        pk[q] = rpk;                                                          \
      }                                                                       \
      *(uint4v*)(As[NXBUF] + row * 64 + swst) = pk;                           \
    } } while (0)

  // prologue: chunk 0 (s0, diff-lo) into buf0
  GLDS_TILE(As[0], diff_sw + ((size_t)(bt * 16 + s0) * 2 + 0) * 8192);
  GLDS_TILE(Bs[0], Wjt_sw + ((size_t)(h * 16 + s0) * 4 + 0) * 8192);
  __syncthreads();

  for (int si = 0; si < scount; ++si) {
    int s = s0 + si;
    int sn = (s + 1 < S_) ? s + 1 : 0;  // wrap: staged junk never computed
    // ---- phase 0: compute (s,p0) from buf0; stage (s,p1)->buf1; load se-lo
#pragma unroll
    for (int i = 0; i < 4; ++i)
      raL[i] = *(const ushort8*)(se + aoff_s[i] + s * D_);
    GLDS_TILE(As[1], diff_sw + ((size_t)(bt * 16 + s) * 2 + 1) * 8192);
    GLDS_TILE(Bs[1], Wjt_sw + ((size_t)(h * 16 + s) * 4 + 1) * 8192);
    COMPUTE(0);
    __syncthreads();
    // ---- phase 1: compute (s,p1) from buf1; stage se-lo->buf0; load se-hi
#pragma unroll
    for (int i = 0; i < 4; ++i)
      raH[i] = *(const ushort8*)(se + aoff_s[i] + s * D_ + 64);
    TRANSFORM_WRITE(raL, 0, s, 0);
    GLDS_TILE(Bs[0], Wjt_sw + ((size_t)(h * 16 + s) * 4 + 2) * 8192);
    COMPUTE(1);
    __syncthreads();
    // ---- phase 2: compute (s,p2) from buf0; stage se-hi->buf1
    TRANSFORM_WRITE(raH, 1, s, 1);
    GLDS_TILE(Bs[1], Wjt_sw + ((size_t)(h * 16 + s) * 4 + 3) * 8192);
    COMPUTE(0);
    __syncthreads();
    // ---- phase 3: compute (s,p3) from buf1; stage (s+1,p0)->buf0
    GLDS_TILE(As[0], diff_sw + ((size_t)(bt * 16 + sn) * 2 + 0) * 8192);
    GLDS_TILE(Bs[0], Wjt_sw + ((size_t)(h * 16 + sn) * 4 + 0) * 8192);
    COMPUTE(1);
    __syncthreads();
  }

#pragma unroll
  for (int i = 0; i < 4; ++i)
#pragma unroll
    for (int j = 0; j < 4; ++j)
#pragma unroll
      for (int rr = 0; rr < 4; ++rr) {
        int b_g = bt * 128 + wm * 64 + i * 16 + lg * 4 + rr;
        int o = wn * 64 + j * 16 + l15;
        outp[(((size_t)sh * N_ + b_g) * H_ + h) * D_ + o] = acc[i][j][rr];
      }
}

// ---------------------------------------------------------------------------
// K4: combine nsplit K-partials, LN2 over (H,D)=1024 per b, PReLU, f32 out
// ---------------------------------------------------------------------------
__global__ __launch_bounds__(256) void k_ln2(const float* __restrict__ outp,
                                             const float* __restrict__ ln2w,
                                             const float* __restrict__ ln2b,
                                             const float* __restrict__ pa2,
                                             float* __restrict__ out,
                                             int nsplit) {
  int b = blockIdx.x, t = threadIdx.x;
  __shared__ float red[8];
  __shared__ float stats[2];
  f32x4 v = (f32x4)(0.f);
  for (int p = 0; p < nsplit; ++p)
    v += *((const f32x4*)(outp + (size_t)p * (N_ * 1024) + (size_t)b * 1024) + t);
  float s1 = v[0] + v[1] + v[2] + v[3];
  float s2 = v[0] * v[0] + v[1] * v[1] + v[2] * v[2] + v[3] * v[3];
#pragma unroll
  for (int m = 1; m <= 32; m <<= 1) {
    s1 += __shfl_xor(s1, m);
    s2 += __shfl_xor(s2, m);
  }
  int wave = t >> 6, lane = t & 63;
  if (lane == 0) { red[wave] = s1; red[4 + wave] = s2; }
  __syncthreads();
  if (t == 0) {
    float S = red[0] + red[1] + red[2] + red[3];
    float Q = red[4] + red[5] + red[6] + red[7];
    float mu = S * (1.f / 1024.f);
    float var = Q * (1.f / 1024.f) - mu * mu;
    stats[0] = mu; stats[1] = rsqrtf(var + EPS_);
  }
  __syncthreads();
  float mu = stats[0], rstd = stats[1];
  float a2 = pa2[0];
  f32x4 wv = *((const f32x4*)ln2w + t);
  f32x4 bv = *((const f32x4*)ln2b + t);
  f32x4 r;
#pragma unroll
  for (int e = 0; e < 4; ++e) {
    float y = (v[e] - mu) * rstd * wv[e] + bv[e];
    r[e] = (y >= 0.f) ? y : a2 * y;
  }
  *((f32x4*)(out + (size_t)b * 1024) + t) = r;
}

// ---------------------------------------------------------------------------
extern "C" void kernel_launch(void* const* d_in, const int* in_sizes, int n_in,
                              void* d_out, int out_size, void* d_ws, size_t ws_size,
                              hipStream_t stream) {
  const float* x    = (const float*)d_in[0];
  const float* Wi   = (const float*)d_in[1];
  const float* Wj   = (const float*)d_in[2];
  const float* ln1w = (const float*)d_in[3];
  const float* ln1b = (const float*)d_in[4];
  const float* pa1  = (const float*)d_in[5];
  const float* ln2w = (const float*)d_in[6];
  const float* ln2b = (const float*)d_in[7];
  const float* pa2  = (const float*)d_in[8];
  char* ws = (char*)d_ws;
  // ws layout with liveness overlay:
  //   [0,64M)          se      (gemm1 -> gemm2)
  //   [64M,72M)        diff_sw (prep -> gemm2)
  //   [72M,80M)        Wjt_sw  (castW -> gemm2)
  //   [80M,80M+ns*8M)  outp    (gemm2 -> ln2), OVERLAYS (dead before gemm2):
  //       [80M,88M)     enc_sw  (prep -> gemm1)
  //       [88M,92M)     Wit_sw  (castW -> gemm1)
  //       [92M,93M)     ssum    (gemm1 -> finalize)
  //       [93M,94M)     ssq
  //   [80M+ns*8M, +128K) mr    (finalize -> gemm2; must NOT overlay outp)
  ushortT* se      = (ushortT*)(ws + 0);
  ushortT* diff_sw = (ushortT*)(ws + 67108864);
  ushortT* Wjt_sw  = (ushortT*)(ws + 75497472);
  float*   outp    = (float*)(ws + 83886080);
  ushortT* enc_sw  = (ushortT*)(ws + 83886080);
  ushortT* Wit_sw  = (ushortT*)(ws + 92274688);
  float*   ssum    = (float*)(ws + 96468992);
  float*   ssq     = (float*)(ws + 97517568);
  float*   out     = (float*)d_out;

  int nsplit = (ws_size >= 117571584ull) ? 4 : 2;
  int scount = S_ / nsplit;
  float* mr = (float*)(ws + 83886080 + (size_t)nsplit * 8388608);

  hipLaunchKernelGGL(k_prep, dim3(1024), dim3(256), 0, stream, x, enc_sw, diff_sw);
  hipLaunchKernelGGL(k_castW, dim3(256), dim3(256), 0, stream, Wi, Wj, Wit_sw, Wjt_sw);
  hipLaunchKernelGGL(k_gemm1, dim3(16, 16, 8), dim3(256), 0, stream, enc_sw, Wit_sw, se, ssum, ssq);
  hipLaunchKernelGGL(k_finalize, dim3(64), dim3(256), 0, stream, ssum, ssq, mr);
  hipLaunchKernelGGL(k_gemm2, dim3(16, nsplit, 8), dim3(256), 0, stream, diff_sw, se, Wjt_sw, mr,
                     ln1w, ln1b, pa1, outp, scount);
  hipLaunchKernelGGL(k_ln2, dim3(2048), dim3(256), 0, stream, outp, ln2w, ln2b, pa2, out, nsplit);
}

// Round 6
// 183.398 us; speedup vs baseline: 1.4227x; 1.0273x over previous
//
#include <hip/hip_runtime.h>

#define N_ 2048
#define S_ 16
#define D_ 128
#define H_ 8
#define EPS_ 1e-5f

typedef unsigned short ushortT;
typedef unsigned int uint32;
typedef __attribute__((ext_vector_type(8))) short short8;
typedef __attribute__((ext_vector_type(8))) unsigned short ushort8;
typedef __attribute__((ext_vector_type(4))) float f32x4;
typedef __attribute__((ext_vector_type(4))) unsigned int uint4v;
typedef __attribute__((ext_vector_type(8))) float float8;

__device__ __forceinline__ ushortT f2bf(float f) {
  union { float f; uint32 u; } c; c.f = f;
  uint32 u = c.u;
  u = (u + 0x7FFFu + ((u >> 16) & 1u)) >> 16;  // RNE
  return (ushortT)u;
}
__device__ __forceinline__ float bf2f(ushortT b) {
  union { uint32 u; float f; } c; c.u = ((uint32)b) << 16;
  return c.f;
}

// ---------------------------------------------------------------------------
// K0: per-(n,d) column: stable-descending ranks over S=16.
// enc -> enc_sw fragment order [bt][s][wv]{ ((kk*2+i)*64 + l15*4 + lg)*8 + e }
//   -> per-wave stores are CONTIGUOUS 128B runs; gemm1 reads 16B/lane within
//      a contiguous 2KB region (coalesced both sides).
// diff -> diff_sw glds-linear swizzled tiles [bt128][s][pp][1024 q][8e],
//      q = row*8 + (c8 ^ (row&7)).
// ---------------------------------------------------------------------------
__global__ __launch_bounds__(256) void k_prep(const float* __restrict__ x,
                                              ushortT* __restrict__ enc_sw,
                                              ushortT* __restrict__ diff_sw) {
  int g = blockIdx.x * 256 + threadIdx.x;  // N*D = 262144 threads
  int n = g >> 7, d = g & 127;
  const float* xp = x + (size_t)n * (S_ * D_) + d;
  float v[S_];
#pragma unroll
  for (int s = 0; s < S_; ++s) v[s] = xp[s * D_];
  int r[S_];
#pragma unroll
  for (int i = 0; i < S_; ++i) {
    int ri = 0;
#pragma unroll
    for (int j = 0; j < S_; ++j)
      ri += ((v[j] > v[i]) || (v[j] == v[i] && j < i)) ? 1 : 0;
    r[i] = ri;
  }
  float xs[S_ + 1];
#pragma unroll
  for (int s = 0; s < S_; ++s) {
    float acc = 0.f;
#pragma unroll
    for (int i = 0; i < S_; ++i) acc += (r[i] == s) ? v[i] : 0.f;
    xs[s] = acc;
  }
  xs[S_] = 0.f;
  // enc_sw addressing (fragment order, wave-contiguous)
  int btq = n >> 7, row = n & 127;
  int wv = row >> 5, ii = (row >> 4) & 1, l15n = row & 15;
  int kkm = d >> 5, lgm = (d >> 3) & 3, em = d & 7;
  int off_nd = (((kkm * 2 + ii) * 64) + (l15n * 4 + lgm)) * 8 + em;
  // diff_sw addressing (glds-linear swizzled)
  int pp = d >> 6, c8p = (d >> 3) & 7, ee = d & 7;
  int q = row * 8 + (c8p ^ (row & 7));
#pragma unroll
  for (int s = 0; s < S_; ++s) {
    uint32 mm = 0;
#pragma unroll
    for (int i = 0; i < S_; ++i) mm |= (r[i] <= s) ? (1u << i) : 0u;
    enc_sw[(size_t)((btq * 16 + s) * 4 + wv) * 4096 + off_nd] =
        f2bf((float)mm * (1.f / 65536.f));
    size_t idx = ((((size_t)(btq * 16 + s) * 2 + pp) * 1024) + q) * 8 + ee;
    diff_sw[idx] = f2bf(xs[s] - xs[s + 1]);
  }
}

// ---------------------------------------------------------------------------
// K0b: merged weight casts, 512 threads/block (2 blocks/CU, 16 waves/CU).
// All global stores lane-linear (coalesced); swizzle via inverse-permuted
// LDS reads.
//  blocks [0,128):   Wi[h][s][d][o] -> Wit_sw[hs][q*8], q = o*16 + (cc^(o&7))
//  blocks [128,256): Wj[h][s][dd][o] -> Wjt_sw[hs][part][q*8], q = o*8+(c8^(o&7))
// ---------------------------------------------------------------------------
__global__ __launch_bounds__(512) void k_castW(const float* __restrict__ Wi,
                                               const float* __restrict__ Wj,
                                               ushortT* __restrict__ Wit_sw,
                                               ushortT* __restrict__ Wjt_sw) {
  __shared__ ushortT tile[128 * 136];
  int bx = blockIdx.x;
  int t = threadIdx.x;
  if (bx < 128) {
    int hs = bx;
    const float* src = Wi + (size_t)hs * D_ * D_;
#pragma unroll 4
    for (int i = 0; i < 32; ++i) {  // 16384 / 512
      int e = t + 512 * i;
      int dd = e >> 7, o = e & 127;
      tile[dd * 136 + o] = f2bf(src[e]);
    }
    __syncthreads();
    ushortT* dst = Wit_sw + (size_t)hs * 16384;
#pragma unroll
    for (int r8 = 0; r8 < 4; ++r8) {
      int qc = r8 * 512 + t;              // linear chunk 0..2047
      int o = qc >> 4;
      int cc = (qc & 15) ^ (o & 7);       // recovered K-chunk
      uint4v pk;
#pragma unroll
      for (int w = 0; w < 4; ++w) {
        int d0 = cc * 8 + w * 2;
        ushortT lo = tile[d0 * 136 + o];
        ushortT hi = tile[(d0 + 1) * 136 + o];
        pk[w] = (uint32)lo | ((uint32)hi << 16);
      }
      *(uint4v*)(dst + qc * 8) = pk;      // consecutive lanes -> consecutive 16B
    }
  } else {
    int hs = bx - 128;
    const float* src = Wj + (size_t)hs * 256 * D_;
    for (int half = 0; half < 2; ++half) {
      if (half) __syncthreads();
#pragma unroll 4
      for (int i = 0; i < 32; ++i) {
        int e = t + 512 * i;
        int dd = e >> 7, o = e & 127;
        tile[dd * 136 + o] = f2bf(src[half * 16384 + e]);
      }
      __syncthreads();
      ushortT* dstb = Wjt_sw + ((size_t)hs * 4 + half * 2) * 8192;
#pragma unroll
      for (int r8 = 0; r8 < 4; ++r8) {
        int cg = r8 * 512 + t;            // 0..2047
        int pl = cg >> 10;                // part within half
        int qc = cg & 1023;
        int o = qc >> 3;
        int c8 = (qc & 7) ^ (o & 7);
        int dl = pl * 64 + c8 * 8;        // dd_local base
        uint4v pk;
#pragma unroll
        for (int w = 0; w < 4; ++w) {
          ushortT lo = tile[(dl + w * 2) * 136 + o];
          ushortT hi = tile[(dl + w * 2 + 1) * 136 + o];
          pk[w] = (uint32)lo | ((uint32)hi << 16);
        }
        *(uint4v*)(dstb + (size_t)pl * 8192 + qc * 8) = pk;
      }
    }
  }
}

// ---------------------------------------------------------------------------
// K1: se[b,h,s,:] = enc[b,s,:] @ Wi[h,s]; per-(s,b,h) sum/sumsq partials.
// 1 h per block, grid (16,16,8) = 2048 blocks. LDS = 33KB (B-tile via glds,
// A-frags direct from enc_sw, C^T reuses B buffer at stride 132).
// ---------------------------------------------------------------------------
__global__ __launch_bounds__(256, 3) void k_gemm1(const ushortT* __restrict__ enc_sw,
                                                  const ushortT* __restrict__ Wit_sw,
                                                  ushortT* __restrict__ se,
                                                  float* __restrict__ ssum,
                                                  float* __restrict__ ssq) {
  int bt = blockIdx.x, s = blockIdx.y, h = blockIdx.z;
  __shared__ ushortT Bs[128 * 132];  // 33 KB
  int tid = threadIdx.x;
  int wave = tid >> 6, lane = tid & 63;
  int l15 = lane & 15, lg = lane >> 4;

  // stage B tile (32KB) via global_load_lds from pre-swizzled Wit_sw
  const ushortT* bsrc = Wit_sw + (size_t)(h * 16 + s) * 16384;
#pragma unroll
  for (int r8 = 0; r8 < 8; ++r8)
    __builtin_amdgcn_global_load_lds(
        (const __attribute__((address_space(1))) void*)(bsrc + (r8 * 256 + tid) * 8),
        (__attribute__((address_space(3))) void*)(Bs + (r8 * 256 + wave * 64) * 8),
        16, 0, 0);

  // A fragments direct from enc_sw (16B/lane within contiguous 2KB region)
  short8 afr[4][2];
  const ushortT* abase = enc_sw + ((size_t)(bt * 16 + s) * 4 + wave) * 4096;
#pragma unroll
  for (int kk = 0; kk < 4; ++kk)
#pragma unroll
    for (int i = 0; i < 2; ++i)
      afr[kk][i] = *(const short8*)(abase + (((kk * 2 + i) * 64) + (l15 * 4 + lg)) * 8);

  __syncthreads();  // drains glds

  f32x4 acc[2][8];
#pragma unroll
  for (int i = 0; i < 2; ++i)
#pragma unroll
    for (int j = 0; j < 8; ++j) acc[i][j] = (f32x4)(0.f);
#pragma unroll
  for (int kk = 0; kk < 4; ++kk) {
    int cc = kk * 4 + lg;
    short8 b[8];
#pragma unroll
    for (int j = 0; j < 8; ++j) {
      int row = j * 16 + l15;
      b[j] = *(const short8*)(Bs + (row * 16 + (cc ^ (row & 7))) * 8);
    }
#pragma unroll
    for (int i = 0; i < 2; ++i)
#pragma unroll
      for (int j = 0; j < 8; ++j)
        acc[i][j] = __builtin_amdgcn_mfma_f32_16x16x32_bf16(afr[kk][i], b[j], acc[i][j], 0, 0, 0);
  }
  // stats partials
#pragma unroll
  for (int i = 0; i < 2; ++i)
#pragma unroll
    for (int rr = 0; rr < 4; ++rr) {
      int rloc = wave * 32 + i * 16 + lg * 4 + rr;
      int b_g = bt * 128 + rloc;
      float rs = 0.f, rq = 0.f;
#pragma unroll
      for (int j = 0; j < 8; ++j) {
        float val = acc[i][j][rr];
        rs += val; rq += val * val;
      }
#pragma unroll
      for (int m = 1; m <= 8; m <<= 1) {
        rs += __shfl_xor(rs, m);
        rq += __shfl_xor(rq, m);
      }
      if (l15 == 0) {
        ssum[((size_t)s * N_ + b_g) * H_ + h] = rs;
        ssq[((size_t)s * N_ + b_g) * H_ + h] = rq;
      }
    }
  __syncthreads();  // all MFMA reads of Bs done
  // C^T into Bs at stride 132
#pragma unroll
  for (int i = 0; i < 2; ++i)
#pragma unroll
    for (int rr = 0; rr < 4; ++rr) {
      int row = wave * 32 + i * 16 + lg * 4 + rr;
      int sw = (row & 7) << 3;
#pragma unroll
      for (int j = 0; j < 8; ++j) {
        int o = j * 16 + l15;
        Bs[row * 132 + (o ^ sw)] = f2bf(acc[i][j][rr]);
      }
    }
  __syncthreads();
#pragma unroll
  for (int p = 0; p < 2; ++p) {
    int row = p * 64 + (tid >> 2);
    int sw = (row & 7) << 3;
    int b_g = bt * 128 + row;
    ushortT* dst = se + (((size_t)b_g * H_ + h) * S_ + s) * D_;
#pragma unroll
    for (int qq = 0; qq < 4; ++qq) {
      int o0 = (qq * 4 + (tid & 3)) * 8;
      *(uint4v*)(dst + o0) = *(const uint4v*)(Bs + row * 132 + (o0 ^ sw));
    }
  }
}

// ---------------------------------------------------------------------------
// K2: LN1 stats finalize -> (rstd, -mu*rstd) per (b,h)
// ---------------------------------------------------------------------------
__global__ __launch_bounds__(256) void k_finalize(const float* __restrict__ ssum,
                                                  const float* __restrict__ ssq,
                                                  float* __restrict__ mr) {
  int t = blockIdx.x * 256 + threadIdx.x;  // N*H = 16384
  float s1 = 0.f, s2 = 0.f;
#pragma unroll
  for (int s = 0; s < S_; ++s) {
    s1 += ssum[(size_t)s * (N_ * H_) + t];
    s2 += ssq[(size_t)s * (N_ * H_) + t];
  }
  float mu = s1 * (1.f / 2048.f);
  float var = s2 * (1.f / 2048.f) - mu * mu;
  float rstd = rsqrtf(var + EPS_);
  mr[t * 2] = rstd;
  mr[t * 2 + 1] = -mu * rstd;
}

// ---------------------------------------------------------------------------
// K3: out_part[sh] = sum over 8 s of [diff | act(LN1(se))] @ Wj[h,s]
// BM=64 (grid 32x2x8 = 512 blocks, 48KB LDS -> 3 blocks/CU capacity).
// Double-buffered, one __syncthreads per BK=64 chunk; diff/Wjt via glds from
// pre-swizzled layouts; se reg-staged with fused LN1+PReLU. setprio on MFMA.
// ---------------------------------------------------------------------------
#define GLDS_B(DST, SRC) do {                                                 \
    const ushortT* sp_ = (SRC) + wave * 512 + lane * 8;                       \
    ushortT* dp_ = (DST) + wave * 512;                                        \
    _Pragma("unroll")                                                         \
    for (int i_ = 0; i_ < 4; ++i_)                                            \
      __builtin_amdgcn_global_load_lds(                                       \
          (const __attribute__((address_space(1))) void*)(sp_ + i_ * 2048),   \
          (__attribute__((address_space(3))) void*)(dp_ + i_ * 2048),         \
          16, 0, 0);                                                          \
  } while (0)

#define GLDS_A(DST, SRC) do {                                                 \
    const ushortT* sp_ = (SRC) + wave * 512 + lane * 8;                       \
    ushortT* dp_ = (DST) + wave * 512;                                        \
    _Pragma("unroll")                                                         \
    for (int i_ = 0; i_ < 2; ++i_)                                            \
      __builtin_amdgcn_global_load_lds(                                       \
          (const __attribute__((address_space(1))) void*)(sp_ + i_ * 2048),   \
          (__attribute__((address_space(3))) void*)(dp_ + i_ * 2048),         \
          16, 0, 0);                                                          \
  } while (0)

__global__ __launch_bounds__(256, 3) void k_gemm2(const ushortT* __restrict__ diff_sw,
                                                  const ushortT* __restrict__ se,
                                                  const ushortT* __restrict__ Wjt_sw,
                                                  const float* __restrict__ mr,
                                                  const float* __restrict__ ln1w,
                                                  const float* __restrict__ ln1b,
                                                  const float* __restrict__ pa1,
                                                  float* __restrict__ outp) {
  int bt2 = blockIdx.x, sh = blockIdx.y, h = blockIdx.z;
  int s0 = sh * 8;
  __shared__ ushortT As[2][64 * 64];    // 2 x 8 KB
  __shared__ ushortT Bs[2][128 * 64];   // 2 x 16 KB
  int tid = threadIdx.x;
  int wave = tid >> 6, lane = tid & 63;
  int c8 = tid & 7, trow = tid >> 3;    // trow 0..31
  int swst = ((c8 ^ (trow & 7)) * 8);
  int l15 = lane & 15, lg = lane >> 4;
  int wm = wave >> 1, wn = wave & 1;
  float a1 = pa1[0];

  float rs_r[2], nm_r[2];
  uint32 aoff_s[2];
#pragma unroll
  for (int i = 0; i < 2; ++i) {
    int row = i * 32 + trow;
    int b_g = bt2 * 64 + row;
    rs_r[i] = mr[((size_t)b_g * H_ + h) * 2];
    nm_r[i] = mr[((size_t)b_g * H_ + h) * 2 + 1];
    aoff_s[i] = ((uint32)b_g * H_ + h) * (S_ * D_) + c8 * 8;
  }
  // diff_sw half-tile base for this 64-row block
  const ushortT* dbase = diff_sw + (size_t)(bt2 >> 1) * (S_ * 2 * 8192) + (bt2 & 1) * 4096;
  ushort8 raL[2], raH[2];
  f32x4 acc[2][4];
#pragma unroll
  for (int i = 0; i < 2; ++i)
#pragma unroll
    for (int j = 0; j < 4; ++j) acc[i][j] = (f32x4)(0.f);

#define COMPUTE(XBUF) do {                                                    \
    _Pragma("unroll")                                                         \
    for (int kk = 0; kk < 2; ++kk) {                                          \
      int cc = kk * 4 + lg;                                                   \
      short8 a[2], b[4];                                                      \
      _Pragma("unroll")                                                       \
      for (int i = 0; i < 2; ++i) {                                           \
        int row = wm * 32 + i * 16 + l15;                                     \
        a[i] = *(const short8*)(As[XBUF] + row * 64 + ((cc ^ (row & 7)) * 8));\
      }                                                                       \
      _Pragma("unroll")                                                       \
      for (int j = 0; j < 4; ++j) {                                           \
        int row = wn * 64 + j * 16 + l15;                                     \
        b[j] = *(const short8*)(Bs[XBUF] + row * 64 + ((cc ^ (row & 7)) * 8));\
      }                                                                       \
      __builtin_amdgcn_s_setprio(1);                                          \
      _Pragma("unroll")                                                       \
      for (int i = 0; i < 2; ++i)                                             \
        _Pragma("unroll")                                                     \
        for (int j = 0; j < 4; ++j)                                           \
          acc[i][j] = __builtin_amdgcn_mfma_f32_16x16x32_bf16(a[i], b[j],     \
                                                              acc[i][j], 0, 0, 0); \
      __builtin_amdgcn_s_setprio(0);                                          \
    } } while (0)

#define TRANSFORM_WRITE(RA, NXBUF, SS, HALF) do {                             \
    float8 w8 = *(const float8*)(ln1w + (SS) * D_ + (HALF) * 64 + c8 * 8);    \
    float8 b8 = *(const float8*)(ln1b + (SS) * D_ + (HALF) * 64 + c8 * 8);    \
    _Pragma("unroll")                                                         \
    for (int i = 0; i < 2; ++i) {                                             \
      int row = i * 32 + trow;                                                \
      float y[8];                                                             \
      _Pragma("unroll")                                                       \
      for (int e = 0; e < 8; ++e) {                                           \
        float f = bf2f((ushortT)RA[i][e]);                                    \
        float tt = fmaf(f, rs_r[i], nm_r[i]);                                 \
        float vv = fmaf(tt, w8[e], b8[e]);                                    \
        y[e] = fmaf(a1, fminf(vv, 0.f), fmaxf(vv, 0.f));                      \
      }                                                                       \
      uint4v pk;                                                              \
      _Pragma("unroll")                                                       \
      for (int q = 0; q < 4; ++q) {                                           \
        uint32 rpk;                                                           \
        asm("v_cvt_pk_bf16_f32 %0, %1, %2" : "=v"(rpk)                        \
            : "v"(y[2 * q]), "v"(y[2 * q + 1]));                              \
        pk[q] = rpk;                                                          \
      }                                                                       \
      *(uint4v*)(As[NXBUF] + row * 64 + swst) = pk;                           \
    } } while (0)

  // prologue: chunk (s0, diff-lo) into buf0
  GLDS_A(As[0], dbase + ((size_t)s0 * 2 + 0) * 8192);
  GLDS_B(Bs[0], Wjt_sw + ((size_t)(h * 16 + s0) * 4 + 0) * 8192);
  __syncthreads();

  for (int si = 0; si < 8; ++si) {
    int s = s0 + si;
    int sn = (s + 1 < S_) ? s + 1 : 0;  // wrapped prefetch never computed
    // phase 0: compute (s,diff-lo) buf0; stage (s,diff-hi)->buf1; load se-lo
#pragma unroll
    for (int i = 0; i < 2; ++i)
      raL[i] = *(const ushort8*)(se + aoff_s[i] + s * D_);
    GLDS_A(As[1], dbase + ((size_t)s * 2 + 1) * 8192);
    GLDS_B(Bs[1], Wjt_sw + ((size_t)(h * 16 + s) * 4 + 1) * 8192);
    COMPUTE(0);
    __syncthreads();
    // phase 1: compute (s,diff-hi) buf1; se-lo -> buf0; load se-hi
#pragma unroll
    for (int i = 0; i < 2; ++i)
      raH[i] = *(const ushort8*)(se + aoff_s[i] + s * D_ + 64);
    TRANSFORM_WRITE(raL, 0, s, 0);
    GLDS_B(Bs[0], Wjt_sw + ((size_t)(h * 16 + s) * 4 + 2) * 8192);
    COMPUTE(1);
    __syncthreads();
    // phase 2: compute (s,se-lo) buf0; se-hi -> buf1
    TRANSFORM_WRITE(raH, 1, s, 1);
    GLDS_B(Bs[1], Wjt_sw + ((size_t)(h * 16 + s) * 4 + 3) * 8192);
    COMPUTE(0);
    __syncthreads();
    // phase 3: compute (s,se-hi) buf1; stage (s+1,diff-lo)->buf0
    GLDS_A(As[0], dbase + ((size_t)sn * 2 + 0) * 8192);
    GLDS_B(Bs[0], Wjt_sw + ((size_t)(h * 16 + sn) * 4 + 0) * 8192);
    COMPUTE(1);
    __syncthreads();
  }

#pragma unroll
  for (int i = 0; i < 2; ++i)
#pragma unroll
    for (int j = 0; j < 4; ++j)
#pragma unroll
      for (int rr = 0; rr < 4; ++rr) {
        int b_g = bt2 * 64 + wm * 32 + i * 16 + lg * 4 + rr;
        int o = wn * 64 + j * 16 + l15;
        outp[(((size_t)sh * N_ + b_g) * H_ + h) * D_ + o] = acc[i][j][rr];
      }
}

// ---------------------------------------------------------------------------
// K4: combine 2 K-partials, LN2 over (H,D)=1024 per b, PReLU, f32 out
// ---------------------------------------------------------------------------
__global__ __launch_bounds__(256) void k_ln2(const float* __restrict__ outp,
                                             const float* __restrict__ ln2w,
                                             const float* __restrict__ ln2b,
                                             const float* __restrict__ pa2,
                                             float* __restrict__ out) {
  int b = blockIdx.x, t = threadIdx.x;
  __shared__ float red[8];
  __shared__ float stats[2];
  f32x4 v = *((const f32x4*)(outp + (size_t)b * 1024) + t) +
            *((const f32x4*)(outp + (size_t)N_ * 1024 + (size_t)b * 1024) + t);
  float s1 = v[0] + v[1] + v[2] + v[3];
  float s2 = v[0] * v[0] + v[1] * v[1] + v[2] * v[2] + v[3] * v[3];
#pragma unroll
  for (int m = 1; m <= 32; m <<= 1) {
    s1 += __shfl_xor(s1, m);
    s2 += __shfl_xor(s2, m);
  }
  int wave = t >> 6, lane = t & 63;
  if (lane == 0) { red[wave] = s1; red[4 + wave] = s2; }
  __syncthreads();
  if (t == 0) {
    float S = red[0] + red[1] + red[2] + red[3];
    float Q = red[4] + red[5] + red[6] + red[7];
    float mu = S * (1.f / 1024.f);
    float var = Q * (1.f / 1024.f) - mu * mu;
    stats[0] = mu; stats[1] = rsqrtf(var + EPS_);
  }
  __syncthreads();
  float mu = stats[0], rstd = stats[1];
  float a2 = pa2[0];
  f32x4 wv = *((const f32x4*)ln2w + t);
  f32x4 bv = *((const f32x4*)ln2b + t);
  f32x4 r;
#pragma unroll
  for (int e = 0; e < 4; ++e) {
    float y = (v[e] - mu) * rstd * wv[e] + bv[e];
    r[e] = (y >= 0.f) ? y : a2 * y;
  }
  *((f32x4*)(out + (size_t)b * 1024) + t) = r;
}

// ---------------------------------------------------------------------------
extern "C" void kernel_launch(void* const* d_in, const int* in_sizes, int n_in,
                              void* d_out, int out_size, void* d_ws, size_t ws_size,
                              hipStream_t stream) {
  const float* x    = (const float*)d_in[0];
  const float* Wi   = (const float*)d_in[1];
  const float* Wj   = (const float*)d_in[2];
  const float* ln1w = (const float*)d_in[3];
  const float* ln1b = (const float*)d_in[4];
  const float* pa1  = (const float*)d_in[5];
  const float* ln2w = (const float*)d_in[6];
  const float* ln2b = (const float*)d_in[7];
  const float* pa2  = (const float*)d_in[8];
  char* ws = (char*)d_ws;
  // ws layout (no overlays; peak 110.2 MB, ws is 256 MB):
  //   [0,64M)     se       [64M,72M)  diff_sw   [72M,80M)  Wjt_sw
  //   [80M,96M)   outp(2)  [96M,104M) enc_sw    [104M,108M) Wit_sw
  //   [108M,109M) ssum     [109M,110M) ssq      [110M,+128K) mr
  ushortT* se      = (ushortT*)(ws + 0);
  ushortT* diff_sw = (ushortT*)(ws + 67108864);
  ushortT* Wjt_sw  = (ushortT*)(ws + 75497472);
  float*   outp    = (float*)(ws + 83886080);
  ushortT* enc_sw  = (ushortT*)(ws + 100663296);
  ushortT* Wit_sw  = (ushortT*)(ws + 109051904);
  float*   ssum    = (float*)(ws + 113246208);
  float*   ssq     = (float*)(ws + 114294784);
  float*   mr      = (float*)(ws + 115343360);
  float*   out     = (float*)d_out;

  hipLaunchKernelGGL(k_prep, dim3(1024), dim3(256), 0, stream, x, enc_sw, diff_sw);
  hipLaunchKernelGGL(k_castW, dim3(256), dim3(512), 0, stream, Wi, Wj, Wit_sw, Wjt_sw);
  hipLaunchKernelGGL(k_gemm1, dim3(16, 16, 8), dim3(256), 0, stream, enc_sw, Wit_sw, se, ssum, ssq);
  hipLaunchKernelGGL(k_finalize, dim3(64), dim3(256), 0, stream, ssum, ssq, mr);
  hipLaunchKernelGGL(k_gemm2, dim3(32, 2, 8), dim3(256), 0, stream, diff_sw, se, Wjt_sw, mr,
                     ln1w, ln1b, pa1, outp);
  hipLaunchKernelGGL(k_ln2, dim3(2048), dim3(256), 0, stream, outp, ln2w, ln2b, pa2, out);
}